// Round 12
// baseline (133.592 us; speedup 1.0000x reference)
//
#include <hip/hip_runtime.h>
#include <math.h>

#define N_NODES 50000
#define N_EDGES 800000
#define IN_F 128
#define OUT_F 64
#define LRELU_ALPHA 0.2f

#define NPB 128                              // nodes per bucket (power of 2)
#define NBUCK ((N_NODES + NPB - 1) / NPB)    // 391
#define EPT 8                                // edges per thread (hist/scatter)
#define NBT ((N_EDGES / EPT + 255) / 256)    // 391 blocks
#define CHUNK 1024                           // gather chunk (edges)

__device__ inline float wred_max(float v) {
#pragma unroll
    for (int o = 32; o > 0; o >>= 1) v = fmaxf(v, __shfl_down(v, o, 64));
    return v;
}
__device__ inline float wred_sum(float v) {
#pragma unroll
    for (int o = 32; o > 0; o >>= 1) v += __shfl_down(v, o, 64);
    return v;
}

__device__ inline unsigned bf16r(float f) {  // round-to-nearest-even bf16 (as u16)
    unsigned u = __float_as_uint(f);
    u += 0x7fffu + ((u >> 16) & 1u);
    return u >> 16;
}

// K1: Wh = x @ W, register-tiled; emits bf16 Whb. Also s,t dual projections.
// Block 0 additionally zeroes the bucket-histogram counters.
__global__ __launch_bounds__(256, 2) void k_wh(const float* __restrict__ x,
                                               const float* __restrict__ W,
                                               const float* __restrict__ a,
                                               unsigned short* __restrict__ Whb,
                                               float* __restrict__ sv,
                                               float* __restrict__ tv,
                                               int* __restrict__ bcnt) {
    __shared__ float xs[64 * 128];  // x tile, XOR-swizzled
    __shared__ float Ws[128 * 64];  // W, natural layout

    const int tid = threadIdx.x;
    const int row0 = blockIdx.x * 64;

    if (blockIdx.x == 0)
        for (int i = tid; i < NBUCK; i += 256) bcnt[i] = 0;

    for (int i = tid; i < 64 * 32; i += 256) {
        int rl = i >> 5, c4 = (i & 31) << 2;
        int r = row0 + rl;
        float4 v = make_float4(0.f, 0.f, 0.f, 0.f);
        if (r < N_NODES) v = *reinterpret_cast<const float4*>(x + (size_t)r * IN_F + c4);
        int sw = c4 ^ ((rl & 7) << 2);
        *reinterpret_cast<float4*>(&xs[rl * 128 + sw]) = v;
    }
    for (int i = tid; i < 128 * 16; i += 256) {
        int k = i >> 4, c4 = (i & 15) << 2;
        *reinterpret_cast<float4*>(&Ws[k * 64 + c4]) =
            *reinterpret_cast<const float4*>(W + k * 64 + c4);
    }
    __syncthreads();

    const int tx = tid & 15;
    const int ty = tid >> 4;
    const int c0 = tx << 2;
    const int rl0 = ty << 2;

    float acc[4][4] = {};
#pragma unroll 4
    for (int k = 0; k < 128; ++k) {
        float4 b = *reinterpret_cast<const float4*>(&Ws[k * 64 + c0]);
        float a0 = xs[(rl0 + 0) * 128 + (k ^ (((rl0 + 0) & 7) << 2))];
        float a1 = xs[(rl0 + 1) * 128 + (k ^ (((rl0 + 1) & 7) << 2))];
        float a2 = xs[(rl0 + 2) * 128 + (k ^ (((rl0 + 2) & 7) << 2))];
        float a3 = xs[(rl0 + 3) * 128 + (k ^ (((rl0 + 3) & 7) << 2))];
        acc[0][0] = fmaf(a0, b.x, acc[0][0]);
        acc[0][1] = fmaf(a0, b.y, acc[0][1]);
        acc[0][2] = fmaf(a0, b.z, acc[0][2]);
        acc[0][3] = fmaf(a0, b.w, acc[0][3]);
        acc[1][0] = fmaf(a1, b.x, acc[1][0]);
        acc[1][1] = fmaf(a1, b.y, acc[1][1]);
        acc[1][2] = fmaf(a1, b.z, acc[1][2]);
        acc[1][3] = fmaf(a1, b.w, acc[1][3]);
        acc[2][0] = fmaf(a2, b.x, acc[2][0]);
        acc[2][1] = fmaf(a2, b.y, acc[2][1]);
        acc[2][2] = fmaf(a2, b.z, acc[2][2]);
        acc[2][3] = fmaf(a2, b.w, acc[2][3]);
        acc[3][0] = fmaf(a3, b.x, acc[3][0]);
        acc[3][1] = fmaf(a3, b.y, acc[3][1]);
        acc[3][2] = fmaf(a3, b.z, acc[3][2]);
        acc[3][3] = fmaf(a3, b.w, acc[3][3]);
    }

    float at[4], ab[4];
#pragma unroll
    for (int i = 0; i < 4; i++) {
        at[i] = a[c0 + i];
        ab[i] = a[OUT_F + c0 + i];
    }

#pragma unroll
    for (int ri = 0; ri < 4; ++ri) {
        int r = row0 + rl0 + ri;
        float ps = 0.0f, pt = 0.0f;
#pragma unroll
        for (int ci = 0; ci < 4; ++ci) {
            ps = fmaf(acc[ri][ci], at[ci], ps);
            pt = fmaf(acc[ri][ci], ab[ci], pt);
        }
#pragma unroll
        for (int o = 1; o < 16; o <<= 1) {
            ps += __shfl_xor(ps, o, 64);
            pt += __shfl_xor(pt, o, 64);
        }
        if (r < N_NODES) {
            uint2 pk;
            pk.x = bf16r(acc[ri][0]) | (bf16r(acc[ri][1]) << 16);
            pk.y = bf16r(acc[ri][2]) | (bf16r(acc[ri][3]) << 16);
            *reinterpret_cast<uint2*>(Whb + (size_t)r * OUT_F + c0) = pk;
            if (tx == 0) { sv[r] = ps; tv[r] = pt; }
        }
    }
}

// bucket histogram: LDS pre-aggregation, then one global atomic per bucket
__global__ __launch_bounds__(256) void k_bhist(const int* __restrict__ src,
                                               int* __restrict__ bcnt) {
    __shared__ int c[NBUCK];
    for (int i = threadIdx.x; i < NBUCK; i += 256) c[i] = 0;
    __syncthreads();
    int t = blockIdx.x * 256 + threadIdx.x;
    int j0 = t * EPT;
    if (j0 < N_EDGES) {
        int4 a4 = *reinterpret_cast<const int4*>(src + j0);
        int4 b4 = *reinterpret_cast<const int4*>(src + j0 + 4);
        atomicAdd(&c[a4.x >> 7], 1);
        atomicAdd(&c[a4.y >> 7], 1);
        atomicAdd(&c[a4.z >> 7], 1);
        atomicAdd(&c[a4.w >> 7], 1);
        atomicAdd(&c[b4.x >> 7], 1);
        atomicAdd(&c[b4.y >> 7], 1);
        atomicAdd(&c[b4.z >> 7], 1);
        atomicAdd(&c[b4.w >> 7], 1);
    }
    __syncthreads();
    for (int i = threadIdx.x; i < NBUCK; i += 256) {
        int v = c[i];
        if (v) atomicAdd(&bcnt[i], v);
    }
}

// exclusive scan of 391 bucket counts (single 512-thread block)
__global__ __launch_bounds__(512) void k_bscan(const int* __restrict__ bcnt,
                                               int* __restrict__ bbase,
                                               int* __restrict__ cursor) {
    __shared__ int s[512];
    int t = threadIdx.x;
    int c = (t < NBUCK) ? bcnt[t] : 0;
    s[t] = c;
    __syncthreads();
#pragma unroll
    for (int o = 1; o < 512; o <<= 1) {
        int v = (t >= o) ? s[t - o] : 0;
        __syncthreads();
        s[t] += v;
        __syncthreads();
    }
    if (t < NBUCK) {
        int ex = s[t] - c;
        bbase[t] = ex;
        cursor[t] = ex;
    }
    if (t == 0) bbase[NBUCK] = N_EDGES;
}

// bucket scatter: LDS ranks + one global reserve atomic per (block,bucket),
// contiguous run writes; fused edge score + online-softmax block stats.
__global__ __launch_bounds__(256) void k_binscatter(const int* __restrict__ src,
                                                    const int* __restrict__ dst,
                                                    const float* __restrict__ sv,
                                                    const float* __restrict__ tv,
                                                    int* __restrict__ cursor,
                                                    int2* __restrict__ rec,
                                                    float* __restrict__ pmax,
                                                    float* __restrict__ psum) {
    __shared__ int lcnt[NBUCK];
    __shared__ int lbase[NBUCK];
    const int tid = threadIdx.x;
    for (int i = tid; i < NBUCK; i += 256) lcnt[i] = 0;
    __syncthreads();

    int t = blockIdx.x * 256 + tid;
    int j0 = t * EPT;
    bool ok = (j0 < N_EDGES);  // N_EDGES % EPT == 0 -> all-or-nothing per thread

    int s_[EPT], d_[EPT], rk[EPT];
    float v[EPT];
    float lmax = -INFINITY;
    if (ok) {
        int4 a4 = *reinterpret_cast<const int4*>(src + j0);
        int4 b4 = *reinterpret_cast<const int4*>(src + j0 + 4);
        int4 c4 = *reinterpret_cast<const int4*>(dst + j0);
        int4 e4 = *reinterpret_cast<const int4*>(dst + j0 + 4);
        s_[0] = a4.x; s_[1] = a4.y; s_[2] = a4.z; s_[3] = a4.w;
        s_[4] = b4.x; s_[5] = b4.y; s_[6] = b4.z; s_[7] = b4.w;
        d_[0] = c4.x; d_[1] = c4.y; d_[2] = c4.z; d_[3] = c4.w;
        d_[4] = e4.x; d_[5] = e4.y; d_[6] = e4.z; d_[7] = e4.w;
        float svv[EPT], tvv[EPT];
#pragma unroll
        for (int k = 0; k < EPT; k++) svv[k] = sv[s_[k]];
#pragma unroll
        for (int k = 0; k < EPT; k++) tvv[k] = tv[d_[k]];
#pragma unroll
        for (int k = 0; k < EPT; k++) {
            float vv = svv[k] + tvv[k];
            vv = vv > 0.0f ? vv : LRELU_ALPHA * vv;
            v[k] = vv;
            lmax = fmaxf(lmax, vv);
        }
#pragma unroll
        for (int k = 0; k < EPT; k++) rk[k] = atomicAdd(&lcnt[s_[k] >> 7], 1);
    }
    __syncthreads();

    for (int i = tid; i < NBUCK; i += 256) {
        int c = lcnt[i];
        lbase[i] = c ? atomicAdd(&cursor[i], c) : 0;
    }
    __syncthreads();

    if (ok) {
#pragma unroll
        for (int k = 0; k < EPT; k++) {
            int b = s_[k] >> 7;
            rec[lbase[b] + rk[k]] =
                make_int2(d_[k] | ((s_[k] & (NPB - 1)) << 16), __float_as_int(v[k]));
        }
    }

    // online-softmax block stats
    float wm = wred_max(lmax);
    wm = __shfl(wm, 0, 64);
    float ev = 0.0f;
    if (ok) {
#pragma unroll
        for (int k = 0; k < EPT; k++) ev += expf(v[k] - wm);
    }
    float wsum = wred_sum(ev);

    __shared__ float rmx[4], rsm[4];
    if ((tid & 63) == 0) {
        rmx[tid >> 6] = wm;
        rsm[tid >> 6] = wsum;
    }
    __syncthreads();
    if (tid == 0) {
        float bm = fmaxf(fmaxf(rmx[0], rmx[1]), fmaxf(rmx[2], rmx[3]));
        float bs = 0.0f;
#pragma unroll
        for (int i = 0; i < 4; i++)
            bs += (rmx[i] == -INFINITY) ? 0.0f : rsm[i] * expf(rmx[i] - bm);
        pmax[blockIdx.x] = bm;
        psum[blockIdx.x] = bs;
    }
}

// combine block stats: g[0]=gmax, g[1]=1/sum
__global__ __launch_bounds__(1024) void k_rcombine(const float* __restrict__ pmax,
                                                   const float* __restrict__ psum,
                                                   int n, float* __restrict__ g) {
    __shared__ float red[16];
    __shared__ float gm_s;
    int t = threadIdx.x;
    float lmax = -INFINITY;
    for (int i = t; i < n; i += 1024) lmax = fmaxf(lmax, pmax[i]);
    float wm = wred_max(lmax);
    if ((t & 63) == 0) red[t >> 6] = wm;
    __syncthreads();
    if (t == 0) {
        float m = red[0];
        for (int i = 1; i < 16; i++) m = fmaxf(m, red[i]);
        gm_s = m;
    }
    __syncthreads();
    float gm = gm_s;
    float lsum = 0.0f;
    for (int i = t; i < n; i += 1024)
        lsum += (pmax[i] == -INFINITY) ? 0.0f : psum[i] * expf(pmax[i] - gm);
    float ws = wred_sum(lsum);
    __syncthreads();
    if ((t & 63) == 0) red[t >> 6] = ws;
    __syncthreads();
    if (t == 0) {
        float s = 0.0f;
        for (int i = 0; i < 16; i++) s += red[i];
        g[0] = gm;
        g[1] = 1.0f / s;
    }
}

// bucket gather: in-LDS counting sort + half-wave bf16 accumulate.
// Lane j=lane&31 of half h=lane>>5 handles features (2j,2j+1); per pair of
// edges (i, i+1) one dword load / LDS read / expf serves 2 edges.
__global__ __launch_bounds__(1024) void k_bgather(const int* __restrict__ bbase,
                                                  const int2* __restrict__ rec,
                                                  const float* __restrict__ g,
                                                  const unsigned short* __restrict__ Whb,
                                                  float* __restrict__ out) {
    __shared__ int2 sorted[CHUNK];               // 8 KB
    __shared__ int scnt[NPB], soff[NPB], shead[NPB];

    const int tid = threadIdx.x;
    const int lane = tid & 63, w = tid >> 6;     // wave 0..15
    const int j = lane & 31, h = lane >> 5;      // feature-pair, half id
    const int b = blockIdx.x;
    const float gm = g[0], ginv = g[1];
    const int e0 = bbase[b], e1 = bbase[b + 1];

    float ax[8], ay[8];
#pragma unroll
    for (int k = 0; k < 8; k++) { ax[k] = 0.0f; ay[k] = 0.0f; }

    for (int base = e0; base < e1; base += CHUNK) {
        int m = e1 - base;
        if (m > CHUNK) m = CHUNK;

        // edge record in register; LDS histogram by local node id
        int2 r = make_int2(0, 0);
        int ln = 0;
        if (tid < NPB) scnt[tid] = 0;
        __syncthreads();
        if (tid < m) {
            r = rec[base + tid];
            ln = (r.x >> 16) & (NPB - 1);
            atomicAdd(&scnt[ln], 1);
        }
        __syncthreads();

        // exclusive scan of 128 counters: wave 0, lane t owns nodes 2t,2t+1
        if (tid < 64) {
            int c0 = scnt[2 * tid], c1 = scnt[2 * tid + 1];
            int s = c0 + c1;
            int run = s;
#pragma unroll
            for (int o = 1; o < 64; o <<= 1) {
                int src_ln = (tid >= o) ? (tid - o) : tid;
                int t2 = __shfl(run, src_ln, 64);
                if (tid >= o) run += t2;
            }
            int excl = run - s;
            soff[2 * tid] = excl;
            soff[2 * tid + 1] = excl + c0;
            shead[2 * tid] = excl;
            shead[2 * tid + 1] = excl + c0;
        }
        __syncthreads();

        // re-scatter from register into sorted[] (node-grouped)
        if (tid < m) {
            int pos = atomicAdd(&shead[ln], 1);
            sorted[pos] = make_int2(r.x & 0xFFFF, r.y);
        }
        __syncthreads();

        // wave w accumulates its 8 nodes; 2 edges per instruction via halves
#pragma unroll
        for (int k = 0; k < 8; k++) {
            int node = w * 8 + k;
            int lo = soff[node], c = scnt[node];
            float px = 0.0f, py = 0.0f;
            int i = 0;
            for (; i + 3 < c; i += 4) {           // 4 edges, all valid
                int2 q0 = sorted[lo + i + h];
                int2 q1 = sorted[lo + i + 2 + h];
                const unsigned* p0 =
                    reinterpret_cast<const unsigned*>(Whb + (size_t)q0.x * OUT_F);
                const unsigned* p1 =
                    reinterpret_cast<const unsigned*>(Whb + (size_t)q1.x * OUT_F);
                unsigned u0 = p0[j];
                unsigned u1 = p1[j];
                float att0 = expf(__int_as_float(q0.y) - gm);
                float att1 = expf(__int_as_float(q1.y) - gm);
                px = fmaf(att0, __uint_as_float((u0 & 0xffffu) << 16), px);
                py = fmaf(att0, __uint_as_float(u0 & 0xffff0000u), py);
                px = fmaf(att1, __uint_as_float((u1 & 0xffffu) << 16), px);
                py = fmaf(att1, __uint_as_float(u1 & 0xffff0000u), py);
            }
            for (; i < c; i += 2) {               // tail pair (maybe half-valid)
                int ii = i + h;
                bool val = ii < c;
                int2 q = sorted[lo + (val ? ii : i)];
                const unsigned* p =
                    reinterpret_cast<const unsigned*>(Whb + (size_t)q.x * OUT_F);
                unsigned u = p[j];
                float att = val ? expf(__int_as_float(q.y) - gm) : 0.0f;
                px = fmaf(att, __uint_as_float((u & 0xffffu) << 16), px);
                py = fmaf(att, __uint_as_float(u & 0xffff0000u), py);
            }
            ax[k] += px;
            ay[k] += py;
        }
        __syncthreads();
    }

    // combine halves; lanes h==0 write float2 rows, ELU + ginv fused
#pragma unroll
    for (int k = 0; k < 8; k++) {
        float sx = ax[k] + __shfl_down(ax[k], 32, 64);
        float sy = ay[k] + __shfl_down(ay[k], 32, 64);
        int n = b * NPB + w * 8 + k;
        if (h == 0 && n < N_NODES) {
            float2 v;
            v.x = sx * ginv;
            v.y = sy * ginv;
            v.x = v.x > 0.0f ? v.x : expm1f(v.x);
            v.y = v.y > 0.0f ? v.y : expm1f(v.y);
            *reinterpret_cast<float2*>(out + (size_t)n * OUT_F + 2 * j) = v;
        }
    }
}

extern "C" void kernel_launch(void* const* d_in, const int* in_sizes, int n_in,
                              void* d_out, int out_size, void* d_ws, size_t ws_size,
                              hipStream_t stream) {
    const float* x  = (const float*)d_in[0];
    const int*   ei = (const int*)d_in[1];
    const float* W  = (const float*)d_in[2];
    const float* a  = (const float*)d_in[3];
    float* out = (float*)d_out;

    const int* src = ei;            // edge_index[0]
    const int* dst = ei + N_EDGES;  // edge_index[1]

    unsigned short* Whb = (unsigned short*)d_ws;      // 3,200,000 u16 = 6.4 MB
    float* sv     = (float*)(Whb + (size_t)N_NODES * OUT_F);  // 50,000 f
    float* tv     = sv + N_NODES;                     // 50,000 f
    float* pmax   = tv + N_NODES;                     // 512 f
    float* psum   = pmax + 512;                       // 512 f
    float* g      = psum + 512;                       // 2 f (gmax, ginv)
    int*   bcnt   = (int*)(g + 2);                    // NBUCK i
    int*   bbase  = bcnt + NBUCK;                     // NBUCK+1 i
    int*   cursor = bbase + NBUCK + 1;                // NBUCK i
    // 16B-align rec
    size_t used = (size_t)((char*)(cursor + NBUCK) - (char*)d_ws);
    used = (used + 15) & ~(size_t)15;
    int2*  rec  = (int2*)((char*)d_ws + used);        // 800,000 int2 = 6.4 MB

    k_wh<<<(N_NODES + 63) / 64, 256, 0, stream>>>(x, W, a, Whb, sv, tv, bcnt);
    k_bhist<<<NBT, 256, 0, stream>>>(src, bcnt);
    k_bscan<<<1, 512, 0, stream>>>(bcnt, bbase, cursor);
    k_binscatter<<<NBT, 256, 0, stream>>>(src, dst, sv, tv, cursor, rec, pmax, psum);
    k_rcombine<<<1, 1024, 0, stream>>>(pmax, psum, NBT, g);
    k_bgather<<<NBUCK, 1024, 0, stream>>>(bbase, rec, g, Whb, out);
}

// Round 13
// 130.388 us; speedup vs baseline: 1.0246x; 1.0246x over previous
//
#include <hip/hip_runtime.h>
#include <math.h>

#define N_NODES 50000
#define N_EDGES 800000
#define IN_F 128
#define OUT_F 64
#define LRELU_ALPHA 0.2f

#define NPB 128                              // nodes per bucket (power of 2)
#define NBUCK ((N_NODES + NPB - 1) / NPB)    // 391
#define EPT 8                                // edges per thread (scatter)
#define NBT ((N_EDGES / EPT + 255) / 256)    // 391 blocks
#define CHUNK 2048                           // gather chunk (edges)

__device__ inline float wred_max(float v) {
#pragma unroll
    for (int o = 32; o > 0; o >>= 1) v = fmaxf(v, __shfl_down(v, o, 64));
    return v;
}
__device__ inline float wred_sum(float v) {
#pragma unroll
    for (int o = 32; o > 0; o >>= 1) v += __shfl_down(v, o, 64);
    return v;
}

__device__ inline unsigned bf16r(float f) {  // round-to-nearest-even bf16 (as u16)
    unsigned u = __float_as_uint(f);
    u += 0x7fffu + ((u >> 16) & 1u);
    return u >> 16;
}

// K1: Wh = x @ W register-tiled (bf16 out) + s,t projections + fused bucket
// histogram of 1024 edges per block (bcnt pre-zeroed via hipMemsetAsync).
__global__ __launch_bounds__(256, 2) void k_wh(const float* __restrict__ x,
                                               const float* __restrict__ W,
                                               const float* __restrict__ a,
                                               const int* __restrict__ src,
                                               unsigned short* __restrict__ Whb,
                                               float* __restrict__ sv,
                                               float* __restrict__ tv,
                                               int* __restrict__ bcnt) {
    __shared__ float xs[64 * 128];  // x tile, XOR-swizzled
    __shared__ float Ws[128 * 64];  // W, natural layout
    __shared__ int hc[NBUCK];

    const int tid = threadIdx.x;
    const int row0 = blockIdx.x * 64;

    for (int i = tid; i < NBUCK; i += 256) hc[i] = 0;

    for (int i = tid; i < 64 * 32; i += 256) {
        int rl = i >> 5, c4 = (i & 31) << 2;
        int r = row0 + rl;
        float4 v = make_float4(0.f, 0.f, 0.f, 0.f);
        if (r < N_NODES) v = *reinterpret_cast<const float4*>(x + (size_t)r * IN_F + c4);
        int sw = c4 ^ ((rl & 7) << 2);
        *reinterpret_cast<float4*>(&xs[rl * 128 + sw]) = v;
    }
    for (int i = tid; i < 128 * 16; i += 256) {
        int k = i >> 4, c4 = (i & 15) << 2;
        *reinterpret_cast<float4*>(&Ws[k * 64 + c4]) =
            *reinterpret_cast<const float4*>(W + k * 64 + c4);
    }
    __syncthreads();

    // fused edge histogram: this block's 1024 edges
    {
        int j0 = blockIdx.x * 1024 + tid * 4;
        if (j0 < N_EDGES) {  // N_EDGES % 4 == 0 -> all-or-nothing
            int4 s4 = *reinterpret_cast<const int4*>(src + j0);
            atomicAdd(&hc[s4.x >> 7], 1);
            atomicAdd(&hc[s4.y >> 7], 1);
            atomicAdd(&hc[s4.z >> 7], 1);
            atomicAdd(&hc[s4.w >> 7], 1);
        }
    }

    const int tx = tid & 15;
    const int ty = tid >> 4;
    const int c0 = tx << 2;
    const int rl0 = ty << 2;

    float acc[4][4] = {};
#pragma unroll 4
    for (int k = 0; k < 128; ++k) {
        float4 b = *reinterpret_cast<const float4*>(&Ws[k * 64 + c0]);
        float a0 = xs[(rl0 + 0) * 128 + (k ^ (((rl0 + 0) & 7) << 2))];
        float a1 = xs[(rl0 + 1) * 128 + (k ^ (((rl0 + 1) & 7) << 2))];
        float a2 = xs[(rl0 + 2) * 128 + (k ^ (((rl0 + 2) & 7) << 2))];
        float a3 = xs[(rl0 + 3) * 128 + (k ^ (((rl0 + 3) & 7) << 2))];
        acc[0][0] = fmaf(a0, b.x, acc[0][0]);
        acc[0][1] = fmaf(a0, b.y, acc[0][1]);
        acc[0][2] = fmaf(a0, b.z, acc[0][2]);
        acc[0][3] = fmaf(a0, b.w, acc[0][3]);
        acc[1][0] = fmaf(a1, b.x, acc[1][0]);
        acc[1][1] = fmaf(a1, b.y, acc[1][1]);
        acc[1][2] = fmaf(a1, b.z, acc[1][2]);
        acc[1][3] = fmaf(a1, b.w, acc[1][3]);
        acc[2][0] = fmaf(a2, b.x, acc[2][0]);
        acc[2][1] = fmaf(a2, b.y, acc[2][1]);
        acc[2][2] = fmaf(a2, b.z, acc[2][2]);
        acc[2][3] = fmaf(a2, b.w, acc[2][3]);
        acc[3][0] = fmaf(a3, b.x, acc[3][0]);
        acc[3][1] = fmaf(a3, b.y, acc[3][1]);
        acc[3][2] = fmaf(a3, b.z, acc[3][2]);
        acc[3][3] = fmaf(a3, b.w, acc[3][3]);
    }

    float at[4], ab[4];
#pragma unroll
    for (int i = 0; i < 4; i++) {
        at[i] = a[c0 + i];
        ab[i] = a[OUT_F + c0 + i];
    }

#pragma unroll
    for (int ri = 0; ri < 4; ++ri) {
        int r = row0 + rl0 + ri;
        float ps = 0.0f, pt = 0.0f;
#pragma unroll
        for (int ci = 0; ci < 4; ++ci) {
            ps = fmaf(acc[ri][ci], at[ci], ps);
            pt = fmaf(acc[ri][ci], ab[ci], pt);
        }
#pragma unroll
        for (int o = 1; o < 16; o <<= 1) {
            ps += __shfl_xor(ps, o, 64);
            pt += __shfl_xor(pt, o, 64);
        }
        if (r < N_NODES) {
            uint2 pk;
            pk.x = bf16r(acc[ri][0]) | (bf16r(acc[ri][1]) << 16);
            pk.y = bf16r(acc[ri][2]) | (bf16r(acc[ri][3]) << 16);
            *reinterpret_cast<uint2*>(Whb + (size_t)r * OUT_F + c0) = pk;
            if (tx == 0) { sv[r] = ps; tv[r] = pt; }
        }
    }

    // flush histogram
    __syncthreads();
    for (int i = tid; i < NBUCK; i += 256) {
        int v = hc[i];
        if (v) atomicAdd(&bcnt[i], v);
    }
}

// exclusive scan of 391 bucket counts (single 512-thread block)
__global__ __launch_bounds__(512) void k_bscan(const int* __restrict__ bcnt,
                                               int* __restrict__ bbase,
                                               int* __restrict__ cursor) {
    __shared__ int s[512];
    int t = threadIdx.x;
    int c = (t < NBUCK) ? bcnt[t] : 0;
    s[t] = c;
    __syncthreads();
#pragma unroll
    for (int o = 1; o < 512; o <<= 1) {
        int v = (t >= o) ? s[t - o] : 0;
        __syncthreads();
        s[t] += v;
        __syncthreads();
    }
    if (t < NBUCK) {
        int ex = s[t] - c;
        bbase[t] = ex;
        cursor[t] = ex;
    }
    if (t == 0) bbase[NBUCK] = N_EDGES;
}

// bucket scatter: LDS ranks + one global reserve atomic per (block,bucket),
// contiguous run writes; fused edge score + online-softmax block stats.
__global__ __launch_bounds__(256) void k_binscatter(const int* __restrict__ src,
                                                    const int* __restrict__ dst,
                                                    const float* __restrict__ sv,
                                                    const float* __restrict__ tv,
                                                    int* __restrict__ cursor,
                                                    int2* __restrict__ rec,
                                                    float* __restrict__ pmax,
                                                    float* __restrict__ psum) {
    __shared__ int lcnt[NBUCK];
    __shared__ int lbase[NBUCK];
    const int tid = threadIdx.x;
    for (int i = tid; i < NBUCK; i += 256) lcnt[i] = 0;
    __syncthreads();

    int t = blockIdx.x * 256 + tid;
    int j0 = t * EPT;
    bool ok = (j0 < N_EDGES);  // N_EDGES % EPT == 0 -> all-or-nothing per thread

    int s_[EPT], d_[EPT], rk[EPT];
    float v[EPT];
    float lmax = -INFINITY;
    if (ok) {
        int4 a4 = *reinterpret_cast<const int4*>(src + j0);
        int4 b4 = *reinterpret_cast<const int4*>(src + j0 + 4);
        int4 c4 = *reinterpret_cast<const int4*>(dst + j0);
        int4 e4 = *reinterpret_cast<const int4*>(dst + j0 + 4);
        s_[0] = a4.x; s_[1] = a4.y; s_[2] = a4.z; s_[3] = a4.w;
        s_[4] = b4.x; s_[5] = b4.y; s_[6] = b4.z; s_[7] = b4.w;
        d_[0] = c4.x; d_[1] = c4.y; d_[2] = c4.z; d_[3] = c4.w;
        d_[4] = e4.x; d_[5] = e4.y; d_[6] = e4.z; d_[7] = e4.w;
        float svv[EPT], tvv[EPT];
#pragma unroll
        for (int k = 0; k < EPT; k++) svv[k] = sv[s_[k]];
#pragma unroll
        for (int k = 0; k < EPT; k++) tvv[k] = tv[d_[k]];
#pragma unroll
        for (int k = 0; k < EPT; k++) {
            float vv = svv[k] + tvv[k];
            vv = vv > 0.0f ? vv : LRELU_ALPHA * vv;
            v[k] = vv;
            lmax = fmaxf(lmax, vv);
        }
#pragma unroll
        for (int k = 0; k < EPT; k++) rk[k] = atomicAdd(&lcnt[s_[k] >> 7], 1);
    }
    __syncthreads();

    for (int i = tid; i < NBUCK; i += 256) {
        int c = lcnt[i];
        lbase[i] = c ? atomicAdd(&cursor[i], c) : 0;
    }
    __syncthreads();

    if (ok) {
#pragma unroll
        for (int k = 0; k < EPT; k++) {
            int b = s_[k] >> 7;
            rec[lbase[b] + rk[k]] =
                make_int2(d_[k] | ((s_[k] & (NPB - 1)) << 16), __float_as_int(v[k]));
        }
    }

    // online-softmax block stats
    float wm = wred_max(lmax);
    wm = __shfl(wm, 0, 64);
    float ev = 0.0f;
    if (ok) {
#pragma unroll
        for (int k = 0; k < EPT; k++) ev += expf(v[k] - wm);
    }
    float wsum = wred_sum(ev);

    __shared__ float rmx[4], rsm[4];
    if ((tid & 63) == 0) {
        rmx[tid >> 6] = wm;
        rsm[tid >> 6] = wsum;
    }
    __syncthreads();
    if (tid == 0) {
        float bm = fmaxf(fmaxf(rmx[0], rmx[1]), fmaxf(rmx[2], rmx[3]));
        float bs = 0.0f;
#pragma unroll
        for (int i = 0; i < 4; i++)
            bs += (rmx[i] == -INFINITY) ? 0.0f : rsm[i] * expf(rmx[i] - bm);
        pmax[blockIdx.x] = bm;
        psum[blockIdx.x] = bs;
    }
}

// combine block stats: g[0]=gmax, g[1]=1/sum
__global__ __launch_bounds__(1024) void k_rcombine(const float* __restrict__ pmax,
                                                   const float* __restrict__ psum,
                                                   int n, float* __restrict__ g) {
    __shared__ float red[16];
    __shared__ float gm_s;
    int t = threadIdx.x;
    float lmax = -INFINITY;
    for (int i = t; i < n; i += 1024) lmax = fmaxf(lmax, pmax[i]);
    float wm = wred_max(lmax);
    if ((t & 63) == 0) red[t >> 6] = wm;
    __syncthreads();
    if (t == 0) {
        float m = red[0];
        for (int i = 1; i < 16; i++) m = fmaxf(m, red[i]);
        gm_s = m;
    }
    __syncthreads();
    float gm = gm_s;
    float lsum = 0.0f;
    for (int i = t; i < n; i += 1024)
        lsum += (pmax[i] == -INFINITY) ? 0.0f : psum[i] * expf(pmax[i] - gm);
    float ws = wred_sum(lsum);
    __syncthreads();
    if ((t & 63) == 0) red[t >> 6] = ws;
    __syncthreads();
    if (t == 0) {
        float s = 0.0f;
        for (int i = 0; i < 16; i++) s += red[i];
        g[0] = gm;
        g[1] = 1.0f / s;
    }
}

// bucket gather: in-LDS counting sort (CHUNK=2048, regs hold <=2 recs/thread)
// + half-wave bf16 accumulate unrolled 8 edges/iter (4 row loads in flight).
__global__ __launch_bounds__(1024) void k_bgather(const int* __restrict__ bbase,
                                                  const int2* __restrict__ rec,
                                                  const float* __restrict__ g,
                                                  const unsigned short* __restrict__ Whb,
                                                  float* __restrict__ out) {
    __shared__ int2 sorted[CHUNK];               // 16 KB
    __shared__ int scnt[NPB], soff[NPB], shead[NPB];

    const int tid = threadIdx.x;
    const int lane = tid & 63, w = tid >> 6;     // wave 0..15
    const int j = lane & 31, h = lane >> 5;      // feature-pair, half id
    const int b = blockIdx.x;
    const float gm = g[0], ginv = g[1];
    const int e0 = bbase[b], e1 = bbase[b + 1];

    float ax[8], ay[8];
#pragma unroll
    for (int k = 0; k < 8; k++) { ax[k] = 0.0f; ay[k] = 0.0f; }

    for (int base = e0; base < e1; base += CHUNK) {
        int m = e1 - base;
        if (m > CHUNK) m = CHUNK;

        // stage up to 2 records per thread in registers; LDS histogram
        bool va = (tid < m), vb = (tid + 1024 < m);
        int2 ra = make_int2(0, 0), rb = make_int2(0, 0);
        int lna = 0, lnb = 0;
        if (tid < NPB) scnt[tid] = 0;
        __syncthreads();
        if (va) {
            ra = rec[base + tid];
            lna = (ra.x >> 16) & (NPB - 1);
            atomicAdd(&scnt[lna], 1);
        }
        if (vb) {
            rb = rec[base + tid + 1024];
            lnb = (rb.x >> 16) & (NPB - 1);
            atomicAdd(&scnt[lnb], 1);
        }
        __syncthreads();

        // exclusive scan of 128 counters: wave 0, lane t owns nodes 2t,2t+1
        if (tid < 64) {
            int c0 = scnt[2 * tid], c1 = scnt[2 * tid + 1];
            int s = c0 + c1;
            int run = s;
#pragma unroll
            for (int o = 1; o < 64; o <<= 1) {
                int src_ln = (tid >= o) ? (tid - o) : tid;
                int t2 = __shfl(run, src_ln, 64);
                if (tid >= o) run += t2;
            }
            int excl = run - s;
            soff[2 * tid] = excl;
            soff[2 * tid + 1] = excl + c0;
            shead[2 * tid] = excl;
            shead[2 * tid + 1] = excl + c0;
        }
        __syncthreads();

        // re-scatter from registers into sorted[] (node-grouped)
        if (va) {
            int pos = atomicAdd(&shead[lna], 1);
            sorted[pos] = make_int2(ra.x & 0xFFFF, ra.y);
        }
        if (vb) {
            int pos = atomicAdd(&shead[lnb], 1);
            sorted[pos] = make_int2(rb.x & 0xFFFF, rb.y);
        }
        __syncthreads();

        // wave w accumulates its 8 nodes; 8 edges/iter (4 loads in flight/lane)
#pragma unroll
        for (int k = 0; k < 8; k++) {
            int node = w * 8 + k;
            int lo = soff[node], c = scnt[node];
            float px = 0.0f, py = 0.0f;
            int i = 0;
            for (; i + 7 < c; i += 8) {           // 8 edges, all valid
                int2 q0 = sorted[lo + i + h];
                int2 q1 = sorted[lo + i + 2 + h];
                int2 q2 = sorted[lo + i + 4 + h];
                int2 q3 = sorted[lo + i + 6 + h];
                const unsigned* p0 =
                    reinterpret_cast<const unsigned*>(Whb + (size_t)q0.x * OUT_F);
                const unsigned* p1 =
                    reinterpret_cast<const unsigned*>(Whb + (size_t)q1.x * OUT_F);
                const unsigned* p2 =
                    reinterpret_cast<const unsigned*>(Whb + (size_t)q2.x * OUT_F);
                const unsigned* p3 =
                    reinterpret_cast<const unsigned*>(Whb + (size_t)q3.x * OUT_F);
                unsigned u0 = p0[j];
                unsigned u1 = p1[j];
                unsigned u2 = p2[j];
                unsigned u3 = p3[j];
                float att0 = expf(__int_as_float(q0.y) - gm);
                float att1 = expf(__int_as_float(q1.y) - gm);
                float att2 = expf(__int_as_float(q2.y) - gm);
                float att3 = expf(__int_as_float(q3.y) - gm);
                px = fmaf(att0, __uint_as_float((u0 & 0xffffu) << 16), px);
                py = fmaf(att0, __uint_as_float(u0 & 0xffff0000u), py);
                px = fmaf(att1, __uint_as_float((u1 & 0xffffu) << 16), px);
                py = fmaf(att1, __uint_as_float(u1 & 0xffff0000u), py);
                px = fmaf(att2, __uint_as_float((u2 & 0xffffu) << 16), px);
                py = fmaf(att2, __uint_as_float(u2 & 0xffff0000u), py);
                px = fmaf(att3, __uint_as_float((u3 & 0xffffu) << 16), px);
                py = fmaf(att3, __uint_as_float(u3 & 0xffff0000u), py);
            }
            for (; i < c; i += 2) {               // tail pair (maybe half-valid)
                int ii = i + h;
                bool val = ii < c;
                int2 q = sorted[lo + (val ? ii : i)];
                const unsigned* p =
                    reinterpret_cast<const unsigned*>(Whb + (size_t)q.x * OUT_F);
                unsigned u = p[j];
                float att = val ? expf(__int_as_float(q.y) - gm) : 0.0f;
                px = fmaf(att, __uint_as_float((u & 0xffffu) << 16), px);
                py = fmaf(att, __uint_as_float(u & 0xffff0000u), py);
            }
            ax[k] += px;
            ay[k] += py;
        }
        __syncthreads();
    }

    // combine halves; lanes h==0 write float2 rows, ELU + ginv fused
#pragma unroll
    for (int k = 0; k < 8; k++) {
        float sx = ax[k] + __shfl_down(ax[k], 32, 64);
        float sy = ay[k] + __shfl_down(ay[k], 32, 64);
        int n = b * NPB + w * 8 + k;
        if (h == 0 && n < N_NODES) {
            float2 v;
            v.x = sx * ginv;
            v.y = sy * ginv;
            v.x = v.x > 0.0f ? v.x : expm1f(v.x);
            v.y = v.y > 0.0f ? v.y : expm1f(v.y);
            *reinterpret_cast<float2*>(out + (size_t)n * OUT_F + 2 * j) = v;
        }
    }
}

extern "C" void kernel_launch(void* const* d_in, const int* in_sizes, int n_in,
                              void* d_out, int out_size, void* d_ws, size_t ws_size,
                              hipStream_t stream) {
    const float* x  = (const float*)d_in[0];
    const int*   ei = (const int*)d_in[1];
    const float* W  = (const float*)d_in[2];
    const float* a  = (const float*)d_in[3];
    float* out = (float*)d_out;

    const int* src = ei;            // edge_index[0]
    const int* dst = ei + N_EDGES;  // edge_index[1]

    unsigned short* Whb = (unsigned short*)d_ws;      // 3,200,000 u16 = 6.4 MB
    float* sv     = (float*)(Whb + (size_t)N_NODES * OUT_F);  // 50,000 f
    float* tv     = sv + N_NODES;                     // 50,000 f
    float* pmax   = tv + N_NODES;                     // 512 f
    float* psum   = pmax + 512;                       // 512 f
    float* g      = psum + 512;                       // 2 f (gmax, ginv)
    int*   bcnt   = (int*)(g + 2);                    // NBUCK i
    int*   bbase  = bcnt + NBUCK;                     // NBUCK+1 i
    int*   cursor = bbase + NBUCK + 1;                // NBUCK i
    // 16B-align rec
    size_t used = (size_t)((char*)(cursor + NBUCK) - (char*)d_ws);
    used = (used + 15) & ~(size_t)15;
    int2*  rec  = (int2*)((char*)d_ws + used);        // 800,000 int2 = 6.4 MB

    hipMemsetAsync(bcnt, 0, NBUCK * sizeof(int), stream);
    k_wh<<<(N_NODES + 63) / 64, 256, 0, stream>>>(x, W, a, src, Whb, sv, tv, bcnt);
    k_bscan<<<1, 512, 0, stream>>>(bcnt, bbase, cursor);
    k_binscatter<<<NBT, 256, 0, stream>>>(src, dst, sv, tv, cursor, rec, pmax, psum);
    k_rcombine<<<1, 1024, 0, stream>>>(pmax, psum, NBT, g);
    k_bgather<<<NBUCK, 1024, 0, stream>>>(bbase, rec, g, Whb, out);
}

// Round 14
// 118.196 us; speedup vs baseline: 1.1303x; 1.1032x over previous
//
#include <hip/hip_runtime.h>
#include <math.h>

#define N_NODES 50000
#define N_EDGES 800000
#define IN_F 128
#define OUT_F 64
#define LRELU_ALPHA 0.2f

#define NPB 128                              // nodes per bucket (power of 2)
#define NBUCK ((N_NODES + NPB - 1) / NPB)    // 391
#define EPT 8                                // edges per thread (scatter)
#define NBT ((N_EDGES / EPT + 255) / 256)    // 391 blocks
#define CHUNK 2048                           // gather chunk (edges)

typedef __attribute__((ext_vector_type(8))) short bf16x8;
typedef __attribute__((ext_vector_type(4))) float f32x4;

__device__ inline float wred_max(float v) {
#pragma unroll
    for (int o = 32; o > 0; o >>= 1) v = fmaxf(v, __shfl_down(v, o, 64));
    return v;
}
__device__ inline float wred_sum(float v) {
#pragma unroll
    for (int o = 32; o > 0; o >>= 1) v += __shfl_down(v, o, 64);
    return v;
}

__device__ inline unsigned bf16r(float f) {  // round-to-nearest-even bf16 (as u16)
    unsigned u = __float_as_uint(f);
    u += 0x7fffu + ((u >> 16) & 1u);
    return u >> 16;
}

// K0: wt = W@a_top, wb = W@a_bot (f32, exact); Wtb[c][k] = bf16(W[k][c])
__global__ __launch_bounds__(128) void k_proj(const float* __restrict__ W,
                                              const float* __restrict__ a,
                                              float* __restrict__ wt,
                                              float* __restrict__ wb,
                                              unsigned short* __restrict__ Wtb) {
    int k = threadIdx.x;  // 0..127
    float s = 0.0f, t = 0.0f;
#pragma unroll
    for (int c4 = 0; c4 < 64; c4 += 4) {
        float4 wv = *reinterpret_cast<const float4*>(W + k * 64 + c4);
        float4 at = *reinterpret_cast<const float4*>(a + c4);
        float4 ab = *reinterpret_cast<const float4*>(a + 64 + c4);
        s = fmaf(wv.w, at.w, fmaf(wv.z, at.z, fmaf(wv.y, at.y, fmaf(wv.x, at.x, s))));
        t = fmaf(wv.w, ab.w, fmaf(wv.z, ab.z, fmaf(wv.y, ab.y, fmaf(wv.x, ab.x, t))));
        Wtb[(c4 + 0) * 128 + k] = (unsigned short)bf16r(wv.x);
        Wtb[(c4 + 1) * 128 + k] = (unsigned short)bf16r(wv.y);
        Wtb[(c4 + 2) * 128 + k] = (unsigned short)bf16r(wv.z);
        Wtb[(c4 + 3) * 128 + k] = (unsigned short)bf16r(wv.w);
    }
    wt[k] = s;
    wb[k] = t;
}

// K1: MFMA GEMM Whb = bf16(x) @ bf16(W) (f32 accum), fused exact f32
// sv=x·wt, tv=x·wb (during staging), fused bucket histogram.
// 64 rows/block, 4 waves: wave w -> rows w*16..w*16+15, all 64 cols.
__global__ __launch_bounds__(256, 4) void k_wh(const float* __restrict__ x,
                                               const unsigned short* __restrict__ Wtb,
                                               const float* __restrict__ wt,
                                               const float* __restrict__ wb,
                                               const int* __restrict__ src,
                                               unsigned short* __restrict__ Whb,
                                               float* __restrict__ sv,
                                               float* __restrict__ tv,
                                               int* __restrict__ bcnt) {
    __shared__ unsigned short xb[64 * 128];   // bf16 x tile, swizzled (16 KB)
    __shared__ unsigned short wtl[64 * 128];  // bf16 W^T, swizzled (16 KB)
    __shared__ int hc[NBUCK];

    const int tid = threadIdx.x;
    const int row0 = blockIdx.x * 64;

    for (int i = tid; i < NBUCK; i += 256) hc[i] = 0;

    // stage W^T (bf16, global) -> wtl swizzled; 1024 blocks of 8 bf16
    for (int ci = tid; ci < 1024; ci += 256) {
        int c = ci >> 4, kb = ci & 15;
        int4 v = *reinterpret_cast<const int4*>(Wtb + ci * 8);
        *reinterpret_cast<int4*>(&wtl[c * 128 + (kb ^ (c & 15)) * 8]) = v;
    }

    // stage x -> xb (bf16, swizzled) + f32 sv/tv partial dots
    const int cc = (tid & 31) << 2;           // this thread's col chunk
    float4 wt4 = *reinterpret_cast<const float4*>(wt + cc);
    float4 wb4 = *reinterpret_cast<const float4*>(wb + cc);
    float ps[8], pt[8];
#pragma unroll
    for (int it = 0; it < 8; ++it) {
        int i = tid + it * 256;
        int rl = i >> 5;                       // local row 0..63
        int r = row0 + rl;
        float4 v = make_float4(0.f, 0.f, 0.f, 0.f);
        if (r < N_NODES) v = *reinterpret_cast<const float4*>(x + (size_t)r * IN_F + cc);
        ps[it] = fmaf(v.w, wt4.w, fmaf(v.z, wt4.z, fmaf(v.y, wt4.y, v.x * wt4.x)));
        pt[it] = fmaf(v.w, wb4.w, fmaf(v.z, wb4.z, fmaf(v.y, wb4.y, v.x * wb4.x)));
        int kb = cc >> 3;
        uint2 pk;
        pk.x = bf16r(v.x) | (bf16r(v.y) << 16);
        pk.y = bf16r(v.z) | (bf16r(v.w) << 16);
        *reinterpret_cast<uint2*>(
            &xb[rl * 128 + (kb ^ (rl & 15)) * 8 + ((cc >> 2) & 1) * 4]) = pk;
    }

    // fused edge histogram: this block's 1024 edges
    {
        int j0 = blockIdx.x * 1024 + tid * 4;
        if (j0 < N_EDGES) {
            int4 s4 = *reinterpret_cast<const int4*>(src + j0);
            atomicAdd(&hc[s4.x >> 7], 1);
            atomicAdd(&hc[s4.y >> 7], 1);
            atomicAdd(&hc[s4.z >> 7], 1);
            atomicAdd(&hc[s4.w >> 7], 1);
        }
    }
    __syncthreads();

    // MFMA compute
    const int l = tid & 63, w = tid >> 6;
    const int rloc0 = w * 16;
    const int arow = rloc0 + (l & 15);        // local row for A frag
    const int kgrp = l >> 4;                  // 0..3
    f32x4 acc[4] = {f32x4{0,0,0,0}, f32x4{0,0,0,0}, f32x4{0,0,0,0}, f32x4{0,0,0,0}};
#pragma unroll
    for (int t = 0; t < 4; ++t) {             // K chunks of 32
        int kb = t * 4 + kgrp;
        bf16x8 af = *reinterpret_cast<const bf16x8*>(
            &xb[arow * 128 + (kb ^ (arow & 15)) * 8]);
#pragma unroll
        for (int ct = 0; ct < 4; ++ct) {      // col tiles of 16
            int brow = ct * 16 + (l & 15);
            bf16x8 bfr = *reinterpret_cast<const bf16x8*>(
                &wtl[brow * 128 + (kb ^ (brow & 15)) * 8]);
            acc[ct] = __builtin_amdgcn_mfma_f32_16x16x32_bf16(af, bfr, acc[ct], 0, 0, 0);
        }
    }

    // epilogue: pack acc -> bf16 Whb; C/D layout row=(l>>4)*4+i, col=l&15
#pragma unroll
    for (int ct = 0; ct < 4; ++ct) {
#pragma unroll
        for (int i = 0; i < 4; ++i) {
            int r = row0 + rloc0 + (l >> 4) * 4 + i;
            if (r < N_NODES)
                Whb[(size_t)r * OUT_F + ct * 16 + (l & 15)] =
                    (unsigned short)bf16r(acc[ct][i]);
        }
    }

    // sv/tv: reduce partials across 32-thread groups (rows (tid>>5)+8*it)
#pragma unroll
    for (int it = 0; it < 8; ++it) {
        float s = ps[it], t2 = pt[it];
#pragma unroll
        for (int o = 1; o < 32; o <<= 1) {
            s += __shfl_xor(s, o, 64);
            t2 += __shfl_xor(t2, o, 64);
        }
        int r = row0 + (tid >> 5) + it * 8;
        if ((tid & 31) == 0 && r < N_NODES) { sv[r] = s; tv[r] = t2; }
    }

    // flush histogram
    __syncthreads();
    for (int i = tid; i < NBUCK; i += 256) {
        int v = hc[i];
        if (v) atomicAdd(&bcnt[i], v);
    }
}

// exclusive scan of 391 bucket counts (single 512-thread block)
__global__ __launch_bounds__(512) void k_bscan(const int* __restrict__ bcnt,
                                               int* __restrict__ bbase,
                                               int* __restrict__ cursor) {
    __shared__ int s[512];
    int t = threadIdx.x;
    int c = (t < NBUCK) ? bcnt[t] : 0;
    s[t] = c;
    __syncthreads();
#pragma unroll
    for (int o = 1; o < 512; o <<= 1) {
        int v = (t >= o) ? s[t - o] : 0;
        __syncthreads();
        s[t] += v;
        __syncthreads();
    }
    if (t < NBUCK) {
        int ex = s[t] - c;
        bbase[t] = ex;
        cursor[t] = ex;
    }
    if (t == 0) bbase[NBUCK] = N_EDGES;
}

// bucket scatter: LDS ranks + one global reserve atomic per (block,bucket),
// contiguous run writes; fused edge score + online-softmax block stats.
__global__ __launch_bounds__(256) void k_binscatter(const int* __restrict__ src,
                                                    const int* __restrict__ dst,
                                                    const float* __restrict__ sv,
                                                    const float* __restrict__ tv,
                                                    int* __restrict__ cursor,
                                                    int2* __restrict__ rec,
                                                    float* __restrict__ pmax,
                                                    float* __restrict__ psum) {
    __shared__ int lcnt[NBUCK];
    __shared__ int lbase[NBUCK];
    const int tid = threadIdx.x;
    for (int i = tid; i < NBUCK; i += 256) lcnt[i] = 0;
    __syncthreads();

    int t = blockIdx.x * 256 + tid;
    int j0 = t * EPT;
    bool ok = (j0 < N_EDGES);

    int s_[EPT], d_[EPT], rk[EPT];
    float v[EPT];
    float lmax = -INFINITY;
    if (ok) {
        int4 a4 = *reinterpret_cast<const int4*>(src + j0);
        int4 b4 = *reinterpret_cast<const int4*>(src + j0 + 4);
        int4 c4 = *reinterpret_cast<const int4*>(dst + j0);
        int4 e4 = *reinterpret_cast<const int4*>(dst + j0 + 4);
        s_[0] = a4.x; s_[1] = a4.y; s_[2] = a4.z; s_[3] = a4.w;
        s_[4] = b4.x; s_[5] = b4.y; s_[6] = b4.z; s_[7] = b4.w;
        d_[0] = c4.x; d_[1] = c4.y; d_[2] = c4.z; d_[3] = c4.w;
        d_[4] = e4.x; d_[5] = e4.y; d_[6] = e4.z; d_[7] = e4.w;
        float svv[EPT], tvv[EPT];
#pragma unroll
        for (int k = 0; k < EPT; k++) svv[k] = sv[s_[k]];
#pragma unroll
        for (int k = 0; k < EPT; k++) tvv[k] = tv[d_[k]];
#pragma unroll
        for (int k = 0; k < EPT; k++) {
            float vv = svv[k] + tvv[k];
            vv = vv > 0.0f ? vv : LRELU_ALPHA * vv;
            v[k] = vv;
            lmax = fmaxf(lmax, vv);
        }
#pragma unroll
        for (int k = 0; k < EPT; k++) rk[k] = atomicAdd(&lcnt[s_[k] >> 7], 1);
    }
    __syncthreads();

    for (int i = tid; i < NBUCK; i += 256) {
        int c = lcnt[i];
        lbase[i] = c ? atomicAdd(&cursor[i], c) : 0;
    }
    __syncthreads();

    if (ok) {
#pragma unroll
        for (int k = 0; k < EPT; k++) {
            int b = s_[k] >> 7;
            rec[lbase[b] + rk[k]] =
                make_int2(d_[k] | ((s_[k] & (NPB - 1)) << 16), __float_as_int(v[k]));
        }
    }

    // online-softmax block stats
    float wm = wred_max(lmax);
    wm = __shfl(wm, 0, 64);
    float ev = 0.0f;
    if (ok) {
#pragma unroll
        for (int k = 0; k < EPT; k++) ev += __expf(v[k] - wm);
    }
    float wsum = wred_sum(ev);

    __shared__ float rmx[4], rsm[4];
    if ((tid & 63) == 0) {
        rmx[tid >> 6] = wm;
        rsm[tid >> 6] = wsum;
    }
    __syncthreads();
    if (tid == 0) {
        float bm = fmaxf(fmaxf(rmx[0], rmx[1]), fmaxf(rmx[2], rmx[3]));
        float bs = 0.0f;
#pragma unroll
        for (int i = 0; i < 4; i++)
            bs += (rmx[i] == -INFINITY) ? 0.0f : rsm[i] * __expf(rmx[i] - bm);
        pmax[blockIdx.x] = bm;
        psum[blockIdx.x] = bs;
    }
}

// combine block stats: g[0]=gmax, g[1]=1/sum
__global__ __launch_bounds__(1024) void k_rcombine(const float* __restrict__ pmax,
                                                   const float* __restrict__ psum,
                                                   int n, float* __restrict__ g) {
    __shared__ float red[16];
    __shared__ float gm_s;
    int t = threadIdx.x;
    float lmax = -INFINITY;
    for (int i = t; i < n; i += 1024) lmax = fmaxf(lmax, pmax[i]);
    float wm = wred_max(lmax);
    if ((t & 63) == 0) red[t >> 6] = wm;
    __syncthreads();
    if (t == 0) {
        float m = red[0];
        for (int i = 1; i < 16; i++) m = fmaxf(m, red[i]);
        gm_s = m;
    }
    __syncthreads();
    float gm = gm_s;
    float lsum = 0.0f;
    for (int i = t; i < n; i += 1024)
        lsum += (pmax[i] == -INFINITY) ? 0.0f : psum[i] * __expf(pmax[i] - gm);
    float ws = wred_sum(lsum);
    __syncthreads();
    if ((t & 63) == 0) red[t >> 6] = ws;
    __syncthreads();
    if (t == 0) {
        float s = 0.0f;
        for (int i = 0; i < 16; i++) s += red[i];
        g[0] = gm;
        g[1] = 1.0f / s;
    }
}

// bucket gather: in-LDS counting sort (CHUNK=2048) + half-wave bf16
// accumulate, 8 edges/iter (4 row loads in flight), __expf.
__global__ __launch_bounds__(1024) void k_bgather(const int* __restrict__ bbase,
                                                  const int2* __restrict__ rec,
                                                  const float* __restrict__ g,
                                                  const unsigned short* __restrict__ Whb,
                                                  float* __restrict__ out) {
    __shared__ int2 sorted[CHUNK];               // 16 KB
    __shared__ int scnt[NPB], soff[NPB], shead[NPB];

    const int tid = threadIdx.x;
    const int lane = tid & 63, w = tid >> 6;     // wave 0..15
    const int j = lane & 31, h = lane >> 5;      // feature-pair, half id
    const int b = blockIdx.x;
    const float gm = g[0], ginv = g[1];
    const int e0 = bbase[b], e1 = bbase[b + 1];

    float ax[8], ay[8];
#pragma unroll
    for (int k = 0; k < 8; k++) { ax[k] = 0.0f; ay[k] = 0.0f; }

    for (int base = e0; base < e1; base += CHUNK) {
        int m = e1 - base;
        if (m > CHUNK) m = CHUNK;

        bool va = (tid < m), vb = (tid + 1024 < m);
        int2 ra = make_int2(0, 0), rb = make_int2(0, 0);
        int lna = 0, lnb = 0;
        if (tid < NPB) scnt[tid] = 0;
        __syncthreads();
        if (va) {
            ra = rec[base + tid];
            lna = (ra.x >> 16) & (NPB - 1);
            atomicAdd(&scnt[lna], 1);
        }
        if (vb) {
            rb = rec[base + tid + 1024];
            lnb = (rb.x >> 16) & (NPB - 1);
            atomicAdd(&scnt[lnb], 1);
        }
        __syncthreads();

        if (tid < 64) {
            int c0 = scnt[2 * tid], c1 = scnt[2 * tid + 1];
            int s = c0 + c1;
            int run = s;
#pragma unroll
            for (int o = 1; o < 64; o <<= 1) {
                int src_ln = (tid >= o) ? (tid - o) : tid;
                int t2 = __shfl(run, src_ln, 64);
                if (tid >= o) run += t2;
            }
            int excl = run - s;
            soff[2 * tid] = excl;
            soff[2 * tid + 1] = excl + c0;
            shead[2 * tid] = excl;
            shead[2 * tid + 1] = excl + c0;
        }
        __syncthreads();

        if (va) {
            int pos = atomicAdd(&shead[lna], 1);
            sorted[pos] = make_int2(ra.x & 0xFFFF, ra.y);
        }
        if (vb) {
            int pos = atomicAdd(&shead[lnb], 1);
            sorted[pos] = make_int2(rb.x & 0xFFFF, rb.y);
        }
        __syncthreads();

#pragma unroll
        for (int k = 0; k < 8; k++) {
            int node = w * 8 + k;
            int lo = soff[node], c = scnt[node];
            float px = 0.0f, py = 0.0f;
            int i = 0;
            for (; i + 7 < c; i += 8) {
                int2 q0 = sorted[lo + i + h];
                int2 q1 = sorted[lo + i + 2 + h];
                int2 q2 = sorted[lo + i + 4 + h];
                int2 q3 = sorted[lo + i + 6 + h];
                const unsigned* p0 =
                    reinterpret_cast<const unsigned*>(Whb + (size_t)q0.x * OUT_F);
                const unsigned* p1 =
                    reinterpret_cast<const unsigned*>(Whb + (size_t)q1.x * OUT_F);
                const unsigned* p2 =
                    reinterpret_cast<const unsigned*>(Whb + (size_t)q2.x * OUT_F);
                const unsigned* p3 =
                    reinterpret_cast<const unsigned*>(Whb + (size_t)q3.x * OUT_F);
                unsigned u0 = p0[j];
                unsigned u1 = p1[j];
                unsigned u2 = p2[j];
                unsigned u3 = p3[j];
                float att0 = __expf(__int_as_float(q0.y) - gm);
                float att1 = __expf(__int_as_float(q1.y) - gm);
                float att2 = __expf(__int_as_float(q2.y) - gm);
                float att3 = __expf(__int_as_float(q3.y) - gm);
                px = fmaf(att0, __uint_as_float((u0 & 0xffffu) << 16), px);
                py = fmaf(att0, __uint_as_float(u0 & 0xffff0000u), py);
                px = fmaf(att1, __uint_as_float((u1 & 0xffffu) << 16), px);
                py = fmaf(att1, __uint_as_float(u1 & 0xffff0000u), py);
                px = fmaf(att2, __uint_as_float((u2 & 0xffffu) << 16), px);
                py = fmaf(att2, __uint_as_float(u2 & 0xffff0000u), py);
                px = fmaf(att3, __uint_as_float((u3 & 0xffffu) << 16), px);
                py = fmaf(att3, __uint_as_float(u3 & 0xffff0000u), py);
            }
            for (; i < c; i += 2) {
                int ii = i + h;
                bool val = ii < c;
                int2 q = sorted[lo + (val ? ii : i)];
                const unsigned* p =
                    reinterpret_cast<const unsigned*>(Whb + (size_t)q.x * OUT_F);
                unsigned u = p[j];
                float att = val ? __expf(__int_as_float(q.y) - gm) : 0.0f;
                px = fmaf(att, __uint_as_float((u & 0xffffu) << 16), px);
                py = fmaf(att, __uint_as_float(u & 0xffff0000u), py);
            }
            ax[k] += px;
            ay[k] += py;
        }
        __syncthreads();
    }

#pragma unroll
    for (int k = 0; k < 8; k++) {
        float sx = ax[k] + __shfl_down(ax[k], 32, 64);
        float sy = ay[k] + __shfl_down(ay[k], 32, 64);
        int n = b * NPB + w * 8 + k;
        if (h == 0 && n < N_NODES) {
            float2 v;
            v.x = sx * ginv;
            v.y = sy * ginv;
            v.x = v.x > 0.0f ? v.x : expm1f(v.x);
            v.y = v.y > 0.0f ? v.y : expm1f(v.y);
            *reinterpret_cast<float2*>(out + (size_t)n * OUT_F + 2 * j) = v;
        }
    }
}

extern "C" void kernel_launch(void* const* d_in, const int* in_sizes, int n_in,
                              void* d_out, int out_size, void* d_ws, size_t ws_size,
                              hipStream_t stream) {
    const float* x  = (const float*)d_in[0];
    const int*   ei = (const int*)d_in[1];
    const float* W  = (const float*)d_in[2];
    const float* a  = (const float*)d_in[3];
    float* out = (float*)d_out;

    const int* src = ei;            // edge_index[0]
    const int* dst = ei + N_EDGES;  // edge_index[1]

    unsigned short* Whb = (unsigned short*)d_ws;      // 3,200,000 u16 = 6.4 MB
    float* sv     = (float*)(Whb + (size_t)N_NODES * OUT_F);  // 50,000 f
    float* tv     = sv + N_NODES;                     // 50,000 f
    float* pmax   = tv + N_NODES;                     // 512 f
    float* psum   = pmax + 512;                       // 512 f
    float* g      = psum + 512;                       // 2 f (gmax, ginv)
    float* wt     = g + 2;                            // 128 f
    float* wb     = wt + 128;                         // 128 f
    int*   bcnt   = (int*)(wb + 128);                 // NBUCK i
    int*   bbase  = bcnt + NBUCK;                     // NBUCK+1 i
    int*   cursor = bbase + NBUCK + 1;                // NBUCK i
    // 16B-align Wtb then rec
    size_t used = (size_t)((char*)(cursor + NBUCK) - (char*)d_ws);
    used = (used + 15) & ~(size_t)15;
    unsigned short* Wtb = (unsigned short*)((char*)d_ws + used);  // 8192 u16
    used += 8192 * sizeof(unsigned short);
    used = (used + 15) & ~(size_t)15;
    int2*  rec  = (int2*)((char*)d_ws + used);        // 800,000 int2 = 6.4 MB

    hipMemsetAsync(bcnt, 0, NBUCK * sizeof(int), stream);
    k_proj<<<1, 128, 0, stream>>>(W, a, wt, wb, Wtb);
    k_wh<<<(N_NODES + 63) / 64, 256, 0, stream>>>(x, Wtb, wt, wb, src, Whb, sv, tv, bcnt);
    k_bscan<<<1, 512, 0, stream>>>(bcnt, bbase, cursor);
    k_binscatter<<<NBT, 256, 0, stream>>>(src, dst, sv, tv, cursor, rec, pmax, psum);
    k_rcombine<<<1, 1024, 0, stream>>>(pmax, psum, NBT, g);
    k_bgather<<<NBUCK, 1024, 0, stream>>>(bbase, rec, g, Whb, out);
}

// Round 15
// 106.432 us; speedup vs baseline: 1.2552x; 1.1105x over previous
//
#include <hip/hip_runtime.h>
#include <math.h>

#define N_NODES 50000
#define N_EDGES 800000
#define IN_F 128
#define OUT_F 64
#define LRELU_ALPHA 0.2f

#define NPB 64                               // nodes per bucket (power of 2)
#define NBUCK ((N_NODES + NPB - 1) / NPB)    // 782
#define EPT 8                                // edges per thread (scatter)
#define NBT ((N_EDGES / EPT + 255) / 256)    // 391 blocks
#define CHUNK 2048                           // gather chunk (edges)

typedef __attribute__((ext_vector_type(8))) short bf16x8;
typedef __attribute__((ext_vector_type(4))) float f32x4;

__device__ inline float wred_max(float v) {
#pragma unroll
    for (int o = 32; o > 0; o >>= 1) v = fmaxf(v, __shfl_down(v, o, 64));
    return v;
}
__device__ inline float wred_sum(float v) {
#pragma unroll
    for (int o = 32; o > 0; o >>= 1) v += __shfl_down(v, o, 64);
    return v;
}

__device__ inline unsigned bf16r(float f) {  // round-to-nearest-even bf16 (as u16)
    unsigned u = __float_as_uint(f);
    u += 0x7fffu + ((u >> 16) & 1u);
    return u >> 16;
}

// K0: wt = W@a_top, wb = W@a_bot (f32, exact); Wtb[c][k] = bf16(W[k][c]);
// also zeroes bcnt (replaces hipMemsetAsync).
__global__ __launch_bounds__(1024) void k_proj(const float* __restrict__ W,
                                               const float* __restrict__ a,
                                               float* __restrict__ wt,
                                               float* __restrict__ wb,
                                               unsigned short* __restrict__ Wtb,
                                               int* __restrict__ bcnt) {
    int k = threadIdx.x;
    if (k < NBUCK) bcnt[k] = 0;
    if (k >= 128) return;
    float s = 0.0f, t = 0.0f;
#pragma unroll
    for (int c4 = 0; c4 < 64; c4 += 4) {
        float4 wv = *reinterpret_cast<const float4*>(W + k * 64 + c4);
        float4 at = *reinterpret_cast<const float4*>(a + c4);
        float4 ab = *reinterpret_cast<const float4*>(a + 64 + c4);
        s = fmaf(wv.w, at.w, fmaf(wv.z, at.z, fmaf(wv.y, at.y, fmaf(wv.x, at.x, s))));
        t = fmaf(wv.w, ab.w, fmaf(wv.z, ab.z, fmaf(wv.y, ab.y, fmaf(wv.x, ab.x, t))));
        Wtb[(c4 + 0) * 128 + k] = (unsigned short)bf16r(wv.x);
        Wtb[(c4 + 1) * 128 + k] = (unsigned short)bf16r(wv.y);
        Wtb[(c4 + 2) * 128 + k] = (unsigned short)bf16r(wv.z);
        Wtb[(c4 + 3) * 128 + k] = (unsigned short)bf16r(wv.w);
    }
    wt[k] = s;
    wb[k] = t;
}

// K1: MFMA GEMM Whb = bf16(x) @ bf16(W) (f32 accum), fused exact f32
// sv=x·wt, tv=x·wb (during staging), fused bucket histogram.
__global__ __launch_bounds__(256, 4) void k_wh(const float* __restrict__ x,
                                               const unsigned short* __restrict__ Wtb,
                                               const float* __restrict__ wt,
                                               const float* __restrict__ wb,
                                               const int* __restrict__ src,
                                               unsigned short* __restrict__ Whb,
                                               float* __restrict__ sv,
                                               float* __restrict__ tv,
                                               int* __restrict__ bcnt) {
    __shared__ unsigned short xb[64 * 128];   // bf16 x tile, swizzled (16 KB)
    __shared__ unsigned short wtl[64 * 128];  // bf16 W^T, swizzled (16 KB)
    __shared__ int hc[NBUCK];

    const int tid = threadIdx.x;
    const int row0 = blockIdx.x * 64;

    for (int i = tid; i < NBUCK; i += 256) hc[i] = 0;

    for (int ci = tid; ci < 1024; ci += 256) {
        int c = ci >> 4, kb = ci & 15;
        int4 v = *reinterpret_cast<const int4*>(Wtb + ci * 8);
        *reinterpret_cast<int4*>(&wtl[c * 128 + (kb ^ (c & 15)) * 8]) = v;
    }

    const int cc = (tid & 31) << 2;
    float4 wt4 = *reinterpret_cast<const float4*>(wt + cc);
    float4 wb4 = *reinterpret_cast<const float4*>(wb + cc);
    float ps[8], pt[8];
#pragma unroll
    for (int it = 0; it < 8; ++it) {
        int i = tid + it * 256;
        int rl = i >> 5;
        int r = row0 + rl;
        float4 v = make_float4(0.f, 0.f, 0.f, 0.f);
        if (r < N_NODES) v = *reinterpret_cast<const float4*>(x + (size_t)r * IN_F + cc);
        ps[it] = fmaf(v.w, wt4.w, fmaf(v.z, wt4.z, fmaf(v.y, wt4.y, v.x * wt4.x)));
        pt[it] = fmaf(v.w, wb4.w, fmaf(v.z, wb4.z, fmaf(v.y, wb4.y, v.x * wb4.x)));
        int kb = cc >> 3;
        uint2 pk;
        pk.x = bf16r(v.x) | (bf16r(v.y) << 16);
        pk.y = bf16r(v.z) | (bf16r(v.w) << 16);
        *reinterpret_cast<uint2*>(
            &xb[rl * 128 + (kb ^ (rl & 15)) * 8 + ((cc >> 2) & 1) * 4]) = pk;
    }

    {
        int j0 = blockIdx.x * 1024 + tid * 4;
        if (j0 < N_EDGES) {
            int4 s4 = *reinterpret_cast<const int4*>(src + j0);
            atomicAdd(&hc[s4.x >> 6], 1);
            atomicAdd(&hc[s4.y >> 6], 1);
            atomicAdd(&hc[s4.z >> 6], 1);
            atomicAdd(&hc[s4.w >> 6], 1);
        }
    }
    __syncthreads();

    const int l = tid & 63, w = tid >> 6;
    const int rloc0 = w * 16;
    const int arow = rloc0 + (l & 15);
    const int kgrp = l >> 4;
    f32x4 acc[4] = {f32x4{0,0,0,0}, f32x4{0,0,0,0}, f32x4{0,0,0,0}, f32x4{0,0,0,0}};
#pragma unroll
    for (int t = 0; t < 4; ++t) {
        int kb = t * 4 + kgrp;
        bf16x8 af = *reinterpret_cast<const bf16x8*>(
            &xb[arow * 128 + (kb ^ (arow & 15)) * 8]);
#pragma unroll
        for (int ct = 0; ct < 4; ++ct) {
            int brow = ct * 16 + (l & 15);
            bf16x8 bfr = *reinterpret_cast<const bf16x8*>(
                &wtl[brow * 128 + (kb ^ (brow & 15)) * 8]);
            acc[ct] = __builtin_amdgcn_mfma_f32_16x16x32_bf16(af, bfr, acc[ct], 0, 0, 0);
        }
    }

#pragma unroll
    for (int ct = 0; ct < 4; ++ct) {
#pragma unroll
        for (int i = 0; i < 4; ++i) {
            int r = row0 + rloc0 + (l >> 4) * 4 + i;
            if (r < N_NODES)
                Whb[(size_t)r * OUT_F + ct * 16 + (l & 15)] =
                    (unsigned short)bf16r(acc[ct][i]);
        }
    }

#pragma unroll
    for (int it = 0; it < 8; ++it) {
        float s = ps[it], t2 = pt[it];
#pragma unroll
        for (int o = 1; o < 32; o <<= 1) {
            s += __shfl_xor(s, o, 64);
            t2 += __shfl_xor(t2, o, 64);
        }
        int r = row0 + (tid >> 5) + it * 8;
        if ((tid & 31) == 0 && r < N_NODES) { sv[r] = s; tv[r] = t2; }
    }

    __syncthreads();
    for (int i = tid; i < NBUCK; i += 256) {
        int v = hc[i];
        if (v) atomicAdd(&bcnt[i], v);
    }
}

// exclusive scan of 782 bucket counts (single 1024-thread block)
__global__ __launch_bounds__(1024) void k_bscan(const int* __restrict__ bcnt,
                                                int* __restrict__ bbase,
                                                int* __restrict__ cursor) {
    __shared__ int s[1024];
    int t = threadIdx.x;
    int c = (t < NBUCK) ? bcnt[t] : 0;
    s[t] = c;
    __syncthreads();
#pragma unroll
    for (int o = 1; o < 1024; o <<= 1) {
        int v = (t >= o) ? s[t - o] : 0;
        __syncthreads();
        s[t] += v;
        __syncthreads();
    }
    if (t < NBUCK) {
        int ex = s[t] - c;
        bbase[t] = ex;
        cursor[t] = ex;
    }
    if (t == 0) bbase[NBUCK] = N_EDGES;
}

// bucket scatter: LDS ranks + one global reserve atomic per (block,bucket),
// contiguous run writes; fused edge score + online-softmax block stats.
__global__ __launch_bounds__(256) void k_binscatter(const int* __restrict__ src,
                                                    const int* __restrict__ dst,
                                                    const float* __restrict__ sv,
                                                    const float* __restrict__ tv,
                                                    int* __restrict__ cursor,
                                                    int2* __restrict__ rec,
                                                    float* __restrict__ pmax,
                                                    float* __restrict__ psum) {
    __shared__ int lcnt[NBUCK];
    __shared__ int lbase[NBUCK];
    const int tid = threadIdx.x;
    for (int i = tid; i < NBUCK; i += 256) lcnt[i] = 0;
    __syncthreads();

    int t = blockIdx.x * 256 + tid;
    int j0 = t * EPT;
    bool ok = (j0 < N_EDGES);

    int s_[EPT], d_[EPT], rk[EPT];
    float v[EPT];
    float lmax = -INFINITY;
    if (ok) {
        int4 a4 = *reinterpret_cast<const int4*>(src + j0);
        int4 b4 = *reinterpret_cast<const int4*>(src + j0 + 4);
        int4 c4 = *reinterpret_cast<const int4*>(dst + j0);
        int4 e4 = *reinterpret_cast<const int4*>(dst + j0 + 4);
        s_[0] = a4.x; s_[1] = a4.y; s_[2] = a4.z; s_[3] = a4.w;
        s_[4] = b4.x; s_[5] = b4.y; s_[6] = b4.z; s_[7] = b4.w;
        d_[0] = c4.x; d_[1] = c4.y; d_[2] = c4.z; d_[3] = c4.w;
        d_[4] = e4.x; d_[5] = e4.y; d_[6] = e4.z; d_[7] = e4.w;
        float svv[EPT], tvv[EPT];
#pragma unroll
        for (int k = 0; k < EPT; k++) svv[k] = sv[s_[k]];
#pragma unroll
        for (int k = 0; k < EPT; k++) tvv[k] = tv[d_[k]];
#pragma unroll
        for (int k = 0; k < EPT; k++) {
            float vv = svv[k] + tvv[k];
            vv = vv > 0.0f ? vv : LRELU_ALPHA * vv;
            v[k] = vv;
            lmax = fmaxf(lmax, vv);
        }
#pragma unroll
        for (int k = 0; k < EPT; k++) rk[k] = atomicAdd(&lcnt[s_[k] >> 6], 1);
    }
    __syncthreads();

    for (int i = tid; i < NBUCK; i += 256) {
        int c = lcnt[i];
        lbase[i] = c ? atomicAdd(&cursor[i], c) : 0;
    }
    __syncthreads();

    if (ok) {
#pragma unroll
        for (int k = 0; k < EPT; k++) {
            int b = s_[k] >> 6;
            rec[lbase[b] + rk[k]] =
                make_int2(d_[k] | ((s_[k] & (NPB - 1)) << 16), __float_as_int(v[k]));
        }
    }

    float wm = wred_max(lmax);
    wm = __shfl(wm, 0, 64);
    float ev = 0.0f;
    if (ok) {
#pragma unroll
        for (int k = 0; k < EPT; k++) ev += __expf(v[k] - wm);
    }
    float wsum = wred_sum(ev);

    __shared__ float rmx[4], rsm[4];
    if ((tid & 63) == 0) {
        rmx[tid >> 6] = wm;
        rsm[tid >> 6] = wsum;
    }
    __syncthreads();
    if (tid == 0) {
        float bm = fmaxf(fmaxf(rmx[0], rmx[1]), fmaxf(rmx[2], rmx[3]));
        float bs = 0.0f;
#pragma unroll
        for (int i = 0; i < 4; i++)
            bs += (rmx[i] == -INFINITY) ? 0.0f : rsm[i] * __expf(rmx[i] - bm);
        pmax[blockIdx.x] = bm;
        psum[blockIdx.x] = bs;
    }
}

// combine block stats: g[0]=gmax, g[1]=1/sum
__global__ __launch_bounds__(1024) void k_rcombine(const float* __restrict__ pmax,
                                                   const float* __restrict__ psum,
                                                   int n, float* __restrict__ g) {
    __shared__ float red[16];
    __shared__ float gm_s;
    int t = threadIdx.x;
    float lmax = -INFINITY;
    for (int i = t; i < n; i += 1024) lmax = fmaxf(lmax, pmax[i]);
    float wm = wred_max(lmax);
    if ((t & 63) == 0) red[t >> 6] = wm;
    __syncthreads();
    if (t == 0) {
        float m = red[0];
        for (int i = 1; i < 16; i++) m = fmaxf(m, red[i]);
        gm_s = m;
    }
    __syncthreads();
    float gm = gm_s;
    float lsum = 0.0f;
    for (int i = t; i < n; i += 1024)
        lsum += (pmax[i] == -INFINITY) ? 0.0f : psum[i] * __expf(pmax[i] - gm);
    float ws = wred_sum(lsum);
    __syncthreads();
    if ((t & 63) == 0) red[t >> 6] = ws;
    __syncthreads();
    if (t == 0) {
        float s = 0.0f;
        for (int i = 0; i < 16; i++) s += red[i];
        g[0] = gm;
        g[1] = 1.0f / s;
    }
}

// bucket gather: NPB=64, 512 threads (8 waves), in-LDS counting sort +
// half-wave bf16 accumulate (8 edges/iter, 4 row loads in flight), __expf.
__global__ __launch_bounds__(512) void k_bgather(const int* __restrict__ bbase,
                                                 const int2* __restrict__ rec,
                                                 const float* __restrict__ g,
                                                 const unsigned short* __restrict__ Whb,
                                                 float* __restrict__ out) {
    __shared__ int2 sorted[CHUNK];               // 16 KB
    __shared__ int scnt[NPB], soff[NPB], shead[NPB];

    const int tid = threadIdx.x;
    const int lane = tid & 63, w = tid >> 6;     // wave 0..7
    const int j = lane & 31, h = lane >> 5;      // feature-pair, half id
    const int b = blockIdx.x;
    const float gm = g[0], ginv = g[1];
    const int e0 = bbase[b], e1 = bbase[b + 1];

    float ax[8], ay[8];
#pragma unroll
    for (int k = 0; k < 8; k++) { ax[k] = 0.0f; ay[k] = 0.0f; }

    for (int base = e0; base < e1; base += CHUNK) {
        int m = e1 - base;
        if (m > CHUNK) m = CHUNK;

        // stage up to 4 records per thread in registers; LDS histogram
        int2 rr[4];
        int ln[4];
        bool vv[4];
        if (tid < NPB) scnt[tid] = 0;
        __syncthreads();
#pragma unroll
        for (int q = 0; q < 4; q++) {
            int idx = tid + q * 512;
            vv[q] = idx < m;
            rr[q] = make_int2(0, 0);
            ln[q] = 0;
            if (vv[q]) {
                rr[q] = rec[base + idx];
                ln[q] = (rr[q].x >> 16) & (NPB - 1);
                atomicAdd(&scnt[ln[q]], 1);
            }
        }
        __syncthreads();

        // exclusive scan of 64 counters in wave 0 (lane t owns counter t)
        if (tid < 64) {
            int c = scnt[tid];
            int run = c;
#pragma unroll
            for (int o = 1; o < 64; o <<= 1) {
                int src_ln = (tid >= o) ? (tid - o) : tid;
                int t2 = __shfl(run, src_ln, 64);
                if (tid >= o) run += t2;
            }
            int excl = run - c;
            soff[tid] = excl;
            shead[tid] = excl;
        }
        __syncthreads();

        // re-scatter from registers into sorted[] (node-grouped)
#pragma unroll
        for (int q = 0; q < 4; q++) {
            if (vv[q]) {
                int pos = atomicAdd(&shead[ln[q]], 1);
                sorted[pos] = make_int2(rr[q].x & 0xFFFF, rr[q].y);
            }
        }
        __syncthreads();

        // wave w accumulates its 8 nodes; 8 edges/iter (4 loads in flight/lane)
#pragma unroll
        for (int k = 0; k < 8; k++) {
            int node = w * 8 + k;
            int lo = soff[node], c = scnt[node];
            float px = 0.0f, py = 0.0f;
            int i = 0;
            for (; i + 7 < c; i += 8) {
                int2 q0 = sorted[lo + i + h];
                int2 q1 = sorted[lo + i + 2 + h];
                int2 q2 = sorted[lo + i + 4 + h];
                int2 q3 = sorted[lo + i + 6 + h];
                const unsigned* p0 =
                    reinterpret_cast<const unsigned*>(Whb + (size_t)q0.x * OUT_F);
                const unsigned* p1 =
                    reinterpret_cast<const unsigned*>(Whb + (size_t)q1.x * OUT_F);
                const unsigned* p2 =
                    reinterpret_cast<const unsigned*>(Whb + (size_t)q2.x * OUT_F);
                const unsigned* p3 =
                    reinterpret_cast<const unsigned*>(Whb + (size_t)q3.x * OUT_F);
                unsigned u0 = p0[j];
                unsigned u1 = p1[j];
                unsigned u2 = p2[j];
                unsigned u3 = p3[j];
                float att0 = __expf(__int_as_float(q0.y) - gm);
                float att1 = __expf(__int_as_float(q1.y) - gm);
                float att2 = __expf(__int_as_float(q2.y) - gm);
                float att3 = __expf(__int_as_float(q3.y) - gm);
                px = fmaf(att0, __uint_as_float((u0 & 0xffffu) << 16), px);
                py = fmaf(att0, __uint_as_float(u0 & 0xffff0000u), py);
                px = fmaf(att1, __uint_as_float((u1 & 0xffffu) << 16), px);
                py = fmaf(att1, __uint_as_float(u1 & 0xffff0000u), py);
                px = fmaf(att2, __uint_as_float((u2 & 0xffffu) << 16), px);
                py = fmaf(att2, __uint_as_float(u2 & 0xffff0000u), py);
                px = fmaf(att3, __uint_as_float((u3 & 0xffffu) << 16), px);
                py = fmaf(att3, __uint_as_float(u3 & 0xffff0000u), py);
            }
            for (; i < c; i += 2) {
                int ii = i + h;
                bool val = ii < c;
                int2 q = sorted[lo + (val ? ii : i)];
                const unsigned* p =
                    reinterpret_cast<const unsigned*>(Whb + (size_t)q.x * OUT_F);
                unsigned u = p[j];
                float att = val ? __expf(__int_as_float(q.y) - gm) : 0.0f;
                px = fmaf(att, __uint_as_float((u & 0xffffu) << 16), px);
                py = fmaf(att, __uint_as_float(u & 0xffff0000u), py);
            }
            ax[k] += px;
            ay[k] += py;
        }
        __syncthreads();
    }

    // combine halves; lanes h==0 write float2 rows, ELU + ginv fused
#pragma unroll
    for (int k = 0; k < 8; k++) {
        float sx = ax[k] + __shfl_down(ax[k], 32, 64);
        float sy = ay[k] + __shfl_down(ay[k], 32, 64);
        int n = b * NPB + w * 8 + k;
        if (h == 0 && n < N_NODES) {
            float2 v;
            v.x = sx * ginv;
            v.y = sy * ginv;
            v.x = v.x > 0.0f ? v.x : expm1f(v.x);
            v.y = v.y > 0.0f ? v.y : expm1f(v.y);
            *reinterpret_cast<float2*>(out + (size_t)n * OUT_F + 2 * j) = v;
        }
    }
}

extern "C" void kernel_launch(void* const* d_in, const int* in_sizes, int n_in,
                              void* d_out, int out_size, void* d_ws, size_t ws_size,
                              hipStream_t stream) {
    const float* x  = (const float*)d_in[0];
    const int*   ei = (const int*)d_in[1];
    const float* W  = (const float*)d_in[2];
    const float* a  = (const float*)d_in[3];
    float* out = (float*)d_out;

    const int* src = ei;            // edge_index[0]
    const int* dst = ei + N_EDGES;  // edge_index[1]

    unsigned short* Whb = (unsigned short*)d_ws;      // 3,200,000 u16 = 6.4 MB
    float* sv     = (float*)(Whb + (size_t)N_NODES * OUT_F);  // 50,000 f
    float* tv     = sv + N_NODES;                     // 50,000 f
    float* pmax   = tv + N_NODES;                     // 512 f
    float* psum   = pmax + 512;                       // 512 f
    float* g      = psum + 512;                       // 2 f (gmax, ginv)
    float* wt     = g + 2;                            // 128 f
    float* wb     = wt + 128;                         // 128 f
    int*   bcnt   = (int*)(wb + 128);                 // NBUCK i
    int*   bbase  = bcnt + NBUCK;                     // NBUCK+1 i
    int*   cursor = bbase + NBUCK + 1;                // NBUCK i
    size_t used = (size_t)((char*)(cursor + NBUCK) - (char*)d_ws);
    used = (used + 15) & ~(size_t)15;
    unsigned short* Wtb = (unsigned short*)((char*)d_ws + used);  // 8192 u16
    used += 8192 * sizeof(unsigned short);
    used = (used + 15) & ~(size_t)15;
    int2*  rec  = (int2*)((char*)d_ws + used);        // 800,000 int2 = 6.4 MB

    k_proj<<<1, 1024, 0, stream>>>(W, a, wt, wb, Wtb, bcnt);
    k_wh<<<(N_NODES + 63) / 64, 256, 0, stream>>>(x, Wtb, wt, wb, src, Whb, sv, tv, bcnt);
    k_bscan<<<1, 1024, 0, stream>>>(bcnt, bbase, cursor);
    k_binscatter<<<NBT, 256, 0, stream>>>(src, dst, sv, tv, cursor, rec, pmax, psum);
    k_rcombine<<<1, 1024, 0, stream>>>(pmax, psum, NBT, g);
    k_bgather<<<NBUCK, 512, 0, stream>>>(bbase, rec, g, Whb, out);
}

// Round 16
// 102.955 us; speedup vs baseline: 1.2976x; 1.0338x over previous
//
#include <hip/hip_runtime.h>
#include <math.h>

#define N_NODES 50000
#define N_EDGES 800000
#define IN_F 128
#define OUT_F 64
#define LRELU_ALPHA 0.2f

#define NPB 64                               // nodes per bucket (power of 2)
#define NBUCK ((N_NODES + NPB - 1) / NPB)    // 782
#define EPT 16                               // edges per thread (scatter)
#define NBT ((N_EDGES / EPT + 255) / 256)    // 196 blocks
#define CHUNK 2048                           // gather chunk (edges)

typedef __attribute__((ext_vector_type(8))) short bf16x8;
typedef __attribute__((ext_vector_type(4))) float f32x4;

__device__ inline float wred_sum(float v) {
#pragma unroll
    for (int o = 32; o > 0; o >>= 1) v += __shfl_down(v, o, 64);
    return v;
}

__device__ inline unsigned bf16r(float f) {  // round-to-nearest-even bf16 (as u16)
    unsigned u = __float_as_uint(f);
    u += 0x7fffu + ((u >> 16) & 1u);
    return u >> 16;
}

// K0: wt = W@a_top, wb = W@a_bot (f32, exact); Wtb[c][k] = bf16(W[k][c]);
// also zeroes bcnt.
__global__ __launch_bounds__(1024) void k_proj(const float* __restrict__ W,
                                               const float* __restrict__ a,
                                               float* __restrict__ wt,
                                               float* __restrict__ wb,
                                               unsigned short* __restrict__ Wtb,
                                               int* __restrict__ bcnt) {
    int k = threadIdx.x;
    if (k < NBUCK) bcnt[k] = 0;
    if (k >= 128) return;
    float s = 0.0f, t = 0.0f;
#pragma unroll
    for (int c4 = 0; c4 < 64; c4 += 4) {
        float4 wv = *reinterpret_cast<const float4*>(W + k * 64 + c4);
        float4 at = *reinterpret_cast<const float4*>(a + c4);
        float4 ab = *reinterpret_cast<const float4*>(a + 64 + c4);
        s = fmaf(wv.w, at.w, fmaf(wv.z, at.z, fmaf(wv.y, at.y, fmaf(wv.x, at.x, s))));
        t = fmaf(wv.w, ab.w, fmaf(wv.z, ab.z, fmaf(wv.y, ab.y, fmaf(wv.x, ab.x, t))));
        Wtb[(c4 + 0) * 128 + k] = (unsigned short)bf16r(wv.x);
        Wtb[(c4 + 1) * 128 + k] = (unsigned short)bf16r(wv.y);
        Wtb[(c4 + 2) * 128 + k] = (unsigned short)bf16r(wv.z);
        Wtb[(c4 + 3) * 128 + k] = (unsigned short)bf16r(wv.w);
    }
    wt[k] = s;
    wb[k] = t;
}

// K1: MFMA GEMM Whb = bf16(x) @ bf16(W) (f32 accum), fused exact f32
// sv=x·wt, tv=x·wb (during staging), fused bucket histogram.
__global__ __launch_bounds__(256, 4) void k_wh(const float* __restrict__ x,
                                               const unsigned short* __restrict__ Wtb,
                                               const float* __restrict__ wt,
                                               const float* __restrict__ wb,
                                               const int* __restrict__ src,
                                               unsigned short* __restrict__ Whb,
                                               float* __restrict__ sv,
                                               float* __restrict__ tv,
                                               int* __restrict__ bcnt) {
    __shared__ unsigned short xb[64 * 128];   // bf16 x tile, swizzled (16 KB)
    __shared__ unsigned short wtl[64 * 128];  // bf16 W^T, swizzled (16 KB)
    __shared__ int hc[NBUCK];

    const int tid = threadIdx.x;
    const int row0 = blockIdx.x * 64;

    for (int i = tid; i < NBUCK; i += 256) hc[i] = 0;

    for (int ci = tid; ci < 1024; ci += 256) {
        int c = ci >> 4, kb = ci & 15;
        int4 v = *reinterpret_cast<const int4*>(Wtb + ci * 8);
        *reinterpret_cast<int4*>(&wtl[c * 128 + (kb ^ (c & 15)) * 8]) = v;
    }

    const int cc = (tid & 31) << 2;
    float4 wt4 = *reinterpret_cast<const float4*>(wt + cc);
    float4 wb4 = *reinterpret_cast<const float4*>(wb + cc);
    float ps[8], pt[8];
#pragma unroll
    for (int it = 0; it < 8; ++it) {
        int i = tid + it * 256;
        int rl = i >> 5;
        int r = row0 + rl;
        float4 v = make_float4(0.f, 0.f, 0.f, 0.f);
        if (r < N_NODES) v = *reinterpret_cast<const float4*>(x + (size_t)r * IN_F + cc);
        ps[it] = fmaf(v.w, wt4.w, fmaf(v.z, wt4.z, fmaf(v.y, wt4.y, v.x * wt4.x)));
        pt[it] = fmaf(v.w, wb4.w, fmaf(v.z, wb4.z, fmaf(v.y, wb4.y, v.x * wb4.x)));
        int kb = cc >> 3;
        uint2 pk;
        pk.x = bf16r(v.x) | (bf16r(v.y) << 16);
        pk.y = bf16r(v.z) | (bf16r(v.w) << 16);
        *reinterpret_cast<uint2*>(
            &xb[rl * 128 + (kb ^ (rl & 15)) * 8 + ((cc >> 2) & 1) * 4]) = pk;
    }

    {
        int j0 = blockIdx.x * 1024 + tid * 4;
        if (j0 < N_EDGES) {
            int4 s4 = *reinterpret_cast<const int4*>(src + j0);
            atomicAdd(&hc[s4.x >> 6], 1);
            atomicAdd(&hc[s4.y >> 6], 1);
            atomicAdd(&hc[s4.z >> 6], 1);
            atomicAdd(&hc[s4.w >> 6], 1);
        }
    }
    __syncthreads();

    const int l = tid & 63, w = tid >> 6;
    const int rloc0 = w * 16;
    const int arow = rloc0 + (l & 15);
    const int kgrp = l >> 4;
    f32x4 acc[4] = {f32x4{0,0,0,0}, f32x4{0,0,0,0}, f32x4{0,0,0,0}, f32x4{0,0,0,0}};
#pragma unroll
    for (int t = 0; t < 4; ++t) {
        int kb = t * 4 + kgrp;
        bf16x8 af = *reinterpret_cast<const bf16x8*>(
            &xb[arow * 128 + (kb ^ (arow & 15)) * 8]);
#pragma unroll
        for (int ct = 0; ct < 4; ++ct) {
            int brow = ct * 16 + (l & 15);
            bf16x8 bfr = *reinterpret_cast<const bf16x8*>(
                &wtl[brow * 128 + (kb ^ (brow & 15)) * 8]);
            acc[ct] = __builtin_amdgcn_mfma_f32_16x16x32_bf16(af, bfr, acc[ct], 0, 0, 0);
        }
    }

#pragma unroll
    for (int ct = 0; ct < 4; ++ct) {
#pragma unroll
        for (int i = 0; i < 4; ++i) {
            int r = row0 + rloc0 + (l >> 4) * 4 + i;
            if (r < N_NODES)
                Whb[(size_t)r * OUT_F + ct * 16 + (l & 15)] =
                    (unsigned short)bf16r(acc[ct][i]);
        }
    }

#pragma unroll
    for (int it = 0; it < 8; ++it) {
        float s = ps[it], t2 = pt[it];
#pragma unroll
        for (int o = 1; o < 32; o <<= 1) {
            s += __shfl_xor(s, o, 64);
            t2 += __shfl_xor(t2, o, 64);
        }
        int r = row0 + (tid >> 5) + it * 8;
        if ((tid & 31) == 0 && r < N_NODES) { sv[r] = s; tv[r] = t2; }
    }

    __syncthreads();
    for (int i = tid; i < NBUCK; i += 256) {
        int v = hc[i];
        if (v) atomicAdd(&bcnt[i], v);
    }
}

// exclusive scan of 782 bucket counts (single 1024-thread block)
__global__ __launch_bounds__(1024) void k_bscan(const int* __restrict__ bcnt,
                                                int* __restrict__ bbase,
                                                int* __restrict__ cursor) {
    __shared__ int s[1024];
    int t = threadIdx.x;
    int c = (t < NBUCK) ? bcnt[t] : 0;
    s[t] = c;
    __syncthreads();
#pragma unroll
    for (int o = 1; o < 1024; o <<= 1) {
        int v = (t >= o) ? s[t - o] : 0;
        __syncthreads();
        s[t] += v;
        __syncthreads();
    }
    if (t < NBUCK) {
        int ex = s[t] - c;
        bbase[t] = ex;
        cursor[t] = ex;
    }
    if (t == 0) bbase[NBUCK] = N_EDGES;
}

// bucket scatter: EPT=16; LDS ranks + one global reserve atomic per
// (block,bucket); stores rec = {dst|local<<16, bits(exp(v))} — exp computed
// ONCE per edge here (gmax cancels algebraically in the softmax quotient).
__global__ __launch_bounds__(256) void k_binscatter(const int* __restrict__ src,
                                                    const int* __restrict__ dst,
                                                    const float* __restrict__ sv,
                                                    const float* __restrict__ tv,
                                                    int* __restrict__ cursor,
                                                    int2* __restrict__ rec,
                                                    float* __restrict__ psum) {
    __shared__ int lcnt[NBUCK];
    __shared__ int lbase[NBUCK];
    const int tid = threadIdx.x;
    for (int i = tid; i < NBUCK; i += 256) lcnt[i] = 0;
    __syncthreads();

    int t = blockIdx.x * 256 + tid;
    int j0 = t * EPT;
    bool ok = (j0 < N_EDGES);  // N_EDGES % EPT == 0 -> all-or-nothing

    int s_[EPT], d_[EPT], rk[EPT];
    float ev[EPT];
    float lsum = 0.0f;
    if (ok) {
#pragma unroll
        for (int q = 0; q < 4; q++) {
            int4 s4 = *reinterpret_cast<const int4*>(src + j0 + q * 4);
            int4 d4 = *reinterpret_cast<const int4*>(dst + j0 + q * 4);
            s_[q * 4 + 0] = s4.x; s_[q * 4 + 1] = s4.y;
            s_[q * 4 + 2] = s4.z; s_[q * 4 + 3] = s4.w;
            d_[q * 4 + 0] = d4.x; d_[q * 4 + 1] = d4.y;
            d_[q * 4 + 2] = d4.z; d_[q * 4 + 3] = d4.w;
        }
        float svv[EPT], tvv[EPT];
#pragma unroll
        for (int k = 0; k < EPT; k++) svv[k] = sv[s_[k]];
#pragma unroll
        for (int k = 0; k < EPT; k++) tvv[k] = tv[d_[k]];
#pragma unroll
        for (int k = 0; k < EPT; k++) {
            float vv = svv[k] + tvv[k];
            vv = vv > 0.0f ? vv : LRELU_ALPHA * vv;
            float e = __expf(vv);
            ev[k] = e;
            lsum += e;
        }
#pragma unroll
        for (int k = 0; k < EPT; k++) rk[k] = atomicAdd(&lcnt[s_[k] >> 6], 1);
    }
    __syncthreads();

    for (int i = tid; i < NBUCK; i += 256) {
        int c = lcnt[i];
        lbase[i] = c ? atomicAdd(&cursor[i], c) : 0;
    }
    __syncthreads();

    if (ok) {
#pragma unroll
        for (int k = 0; k < EPT; k++) {
            int b = s_[k] >> 6;
            rec[lbase[b] + rk[k]] =
                make_int2(d_[k] | ((s_[k] & (NPB - 1)) << 16), __float_as_int(ev[k]));
        }
    }

    // block partial sum of exp(v)
    float wsum = wred_sum(lsum);
    __shared__ float rsm[4];
    if ((tid & 63) == 0) rsm[tid >> 6] = wsum;
    __syncthreads();
    if (tid == 0)
        psum[blockIdx.x] = rsm[0] + rsm[1] + rsm[2] + rsm[3];
}

// sum the 196 block sums -> g[0] = 1/sum
__global__ __launch_bounds__(256) void k_rsum(const float* __restrict__ psum,
                                              int n, float* __restrict__ g) {
    __shared__ float red[4];
    int t = threadIdx.x;
    float lsum = 0.0f;
    for (int i = t; i < n; i += 256) lsum += psum[i];
    float ws = wred_sum(lsum);
    if ((t & 63) == 0) red[t >> 6] = ws;
    __syncthreads();
    if (t == 0) g[0] = 1.0f / (red[0] + red[1] + red[2] + red[3]);
}

// bucket gather: NPB=64, 512 threads (8 waves), in-LDS counting sort +
// half-wave bf16 accumulate (8 edges/iter); att read directly (no exp).
__global__ __launch_bounds__(512) void k_bgather(const int* __restrict__ bbase,
                                                 const int2* __restrict__ rec,
                                                 const float* __restrict__ g,
                                                 const unsigned short* __restrict__ Whb,
                                                 float* __restrict__ out) {
    __shared__ int2 sorted[CHUNK];               // 16 KB
    __shared__ int scnt[NPB], soff[NPB], shead[NPB];

    const int tid = threadIdx.x;
    const int lane = tid & 63, w = tid >> 6;     // wave 0..7
    const int j = lane & 31, h = lane >> 5;      // feature-pair, half id
    const int b = blockIdx.x;
    const float ginv = g[0];
    const int e0 = bbase[b], e1 = bbase[b + 1];

    float ax[8], ay[8];
#pragma unroll
    for (int k = 0; k < 8; k++) { ax[k] = 0.0f; ay[k] = 0.0f; }

    for (int base = e0; base < e1; base += CHUNK) {
        int m = e1 - base;
        if (m > CHUNK) m = CHUNK;

        int2 rr[4];
        int ln[4];
        bool vv[4];
        if (tid < NPB) scnt[tid] = 0;
        __syncthreads();
#pragma unroll
        for (int q = 0; q < 4; q++) {
            int idx = tid + q * 512;
            vv[q] = idx < m;
            rr[q] = make_int2(0, 0);
            ln[q] = 0;
            if (vv[q]) {
                rr[q] = rec[base + idx];
                ln[q] = (rr[q].x >> 16) & (NPB - 1);
                atomicAdd(&scnt[ln[q]], 1);
            }
        }
        __syncthreads();

        if (tid < 64) {
            int c = scnt[tid];
            int run = c;
#pragma unroll
            for (int o = 1; o < 64; o <<= 1) {
                int src_ln = (tid >= o) ? (tid - o) : tid;
                int t2 = __shfl(run, src_ln, 64);
                if (tid >= o) run += t2;
            }
            int excl = run - c;
            soff[tid] = excl;
            shead[tid] = excl;
        }
        __syncthreads();

#pragma unroll
        for (int q = 0; q < 4; q++) {
            if (vv[q]) {
                int pos = atomicAdd(&shead[ln[q]], 1);
                sorted[pos] = make_int2(rr[q].x & 0xFFFF, rr[q].y);
            }
        }
        __syncthreads();

#pragma unroll
        for (int k = 0; k < 8; k++) {
            int node = w * 8 + k;
            int lo = soff[node], c = scnt[node];
            float px = 0.0f, py = 0.0f;
            int i = 0;
            for (; i + 7 < c; i += 8) {
                int2 q0 = sorted[lo + i + h];
                int2 q1 = sorted[lo + i + 2 + h];
                int2 q2 = sorted[lo + i + 4 + h];
                int2 q3 = sorted[lo + i + 6 + h];
                const unsigned* p0 =
                    reinterpret_cast<const unsigned*>(Whb + (size_t)q0.x * OUT_F);
                const unsigned* p1 =
                    reinterpret_cast<const unsigned*>(Whb + (size_t)q1.x * OUT_F);
                const unsigned* p2 =
                    reinterpret_cast<const unsigned*>(Whb + (size_t)q2.x * OUT_F);
                const unsigned* p3 =
                    reinterpret_cast<const unsigned*>(Whb + (size_t)q3.x * OUT_F);
                unsigned u0 = p0[j];
                unsigned u1 = p1[j];
                unsigned u2 = p2[j];
                unsigned u3 = p3[j];
                float att0 = __int_as_float(q0.y);
                float att1 = __int_as_float(q1.y);
                float att2 = __int_as_float(q2.y);
                float att3 = __int_as_float(q3.y);
                px = fmaf(att0, __uint_as_float((u0 & 0xffffu) << 16), px);
                py = fmaf(att0, __uint_as_float(u0 & 0xffff0000u), py);
                px = fmaf(att1, __uint_as_float((u1 & 0xffffu) << 16), px);
                py = fmaf(att1, __uint_as_float(u1 & 0xffff0000u), py);
                px = fmaf(att2, __uint_as_float((u2 & 0xffffu) << 16), px);
                py = fmaf(att2, __uint_as_float(u2 & 0xffff0000u), py);
                px = fmaf(att3, __uint_as_float((u3 & 0xffffu) << 16), px);
                py = fmaf(att3, __uint_as_float(u3 & 0xffff0000u), py);
            }
            for (; i < c; i += 2) {
                int ii = i + h;
                bool val = ii < c;
                int2 q = sorted[lo + (val ? ii : i)];
                const unsigned* p =
                    reinterpret_cast<const unsigned*>(Whb + (size_t)q.x * OUT_F);
                unsigned u = p[j];
                float att = val ? __int_as_float(q.y) : 0.0f;
                px = fmaf(att, __uint_as_float((u & 0xffffu) << 16), px);
                py = fmaf(att, __uint_as_float(u & 0xffff0000u), py);
            }
            ax[k] += px;
            ay[k] += py;
        }
        __syncthreads();
    }

#pragma unroll
    for (int k = 0; k < 8; k++) {
        float sx = ax[k] + __shfl_down(ax[k], 32, 64);
        float sy = ay[k] + __shfl_down(ay[k], 32, 64);
        int n = b * NPB + w * 8 + k;
        if (h == 0 && n < N_NODES) {
            float2 v;
            v.x = sx * ginv;
            v.y = sy * ginv;
            v.x = v.x > 0.0f ? v.x : expm1f(v.x);
            v.y = v.y > 0.0f ? v.y : expm1f(v.y);
            *reinterpret_cast<float2*>(out + (size_t)n * OUT_F + 2 * j) = v;
        }
    }
}

extern "C" void kernel_launch(void* const* d_in, const int* in_sizes, int n_in,
                              void* d_out, int out_size, void* d_ws, size_t ws_size,
                              hipStream_t stream) {
    const float* x  = (const float*)d_in[0];
    const int*   ei = (const int*)d_in[1];
    const float* W  = (const float*)d_in[2];
    const float* a  = (const float*)d_in[3];
    float* out = (float*)d_out;

    const int* src = ei;            // edge_index[0]
    const int* dst = ei + N_EDGES;  // edge_index[1]

    unsigned short* Whb = (unsigned short*)d_ws;      // 3,200,000 u16 = 6.4 MB
    float* sv     = (float*)(Whb + (size_t)N_NODES * OUT_F);  // 50,000 f
    float* tv     = sv + N_NODES;                     // 50,000 f
    float* psum   = tv + N_NODES;                     // 512 f
    float* g      = psum + 512;                       // 1 f (ginv)
    float* wt     = g + 2;                            // 128 f
    float* wb     = wt + 128;                         // 128 f
    int*   bcnt   = (int*)(wb + 128);                 // NBUCK i
    int*   bbase  = bcnt + NBUCK;                     // NBUCK+1 i
    int*   cursor = bbase + NBUCK + 1;                // NBUCK i
    size_t used = (size_t)((char*)(cursor + NBUCK) - (char*)d_ws);
    used = (used + 15) & ~(size_t)15;
    unsigned short* Wtb = (unsigned short*)((char*)d_ws + used);  // 8192 u16
    used += 8192 * sizeof(unsigned short);
    used = (used + 15) & ~(size_t)15;
    int2*  rec  = (int2*)((char*)d_ws + used);        // 800,000 int2 = 6.4 MB

    k_proj<<<1, 1024, 0, stream>>>(W, a, wt, wb, Wtb, bcnt);
    k_wh<<<(N_NODES + 63) / 64, 256, 0, stream>>>(x, Wtb, wt, wb, src, Whb, sv, tv, bcnt);
    k_bscan<<<1, 1024, 0, stream>>>(bcnt, bbase, cursor);
    k_binscatter<<<NBT, 256, 0, stream>>>(src, dst, sv, tv, cursor, rec, psum);
    k_rsum<<<1, 256, 0, stream>>>(psum, NBT, g);
    k_bgather<<<NBUCK, 512, 0, stream>>>(bbase, rec, g, Whb, out);
}

// Round 17
// 102.223 us; speedup vs baseline: 1.3069x; 1.0072x over previous
//
#include <hip/hip_runtime.h>
#include <math.h>

#define N_NODES 50000
#define N_EDGES 800000
#define IN_F 128
#define OUT_F 64
#define LRELU_ALPHA 0.2f

#define NPB 64                               // nodes per bucket (power of 2)
#define NBUCK ((N_NODES + NPB - 1) / NPB)    // 782
#define EPT 16                               // edges per thread (scatter)
#define NBT ((N_EDGES / EPT + 255) / 256)    // 196 blocks
#define CHUNK 2048                           // gather chunk (edges)

typedef __attribute__((ext_vector_type(8))) short bf16x8;
typedef __attribute__((ext_vector_type(4))) float f32x4;

__device__ inline float wred_sum(float v) {
#pragma unroll
    for (int o = 32; o > 0; o >>= 1) v += __shfl_down(v, o, 64);
    return v;
}

__device__ inline unsigned bf16r(float f) {  // round-to-nearest-even bf16 (as u16)
    unsigned u = __float_as_uint(f);
    u += 0x7fffu + ((u >> 16) & 1u);
    return u >> 16;
}

// K1 (fused): per-block W->bf16 swizzled LDS + wt/wb recompute + x->bf16 LDS
// + exact f32 sv/tv + MFMA GEMM -> Whb + fused bucket histogram.
__global__ __launch_bounds__(256, 4) void k_wh(const float* __restrict__ x,
                                               const float* __restrict__ W,
                                               const float* __restrict__ a,
                                               const int* __restrict__ src,
                                               unsigned short* __restrict__ Whb,
                                               float* __restrict__ sv,
                                               float* __restrict__ tv,
                                               int* __restrict__ bcnt) {
    __shared__ unsigned short xb[64 * 128];   // bf16 x tile, swizzled (16 KB)
    __shared__ unsigned short wtl[64 * 128];  // bf16 W^T, swizzled (16 KB)
    __shared__ float wt_s[128], wb_s[128];
    __shared__ int hc[NBUCK];

    const int tid = threadIdx.x;
    const int row0 = blockIdx.x * 64;

    for (int i = tid; i < NBUCK; i += 256) hc[i] = 0;

    // phase A1: stage W (f32 global) -> wtl = bf16 W^T, swizzled
    for (int i = tid; i < 2048; i += 256) {
        int k = i >> 4, c4 = (i & 15) << 2;
        float4 wv = *reinterpret_cast<const float4*>(W + k * 64 + c4);
        int kb = k >> 3, kr = k & 7;
        wtl[(c4 + 0) * 128 + ((kb ^ ((c4 + 0) & 15)) << 3) + kr] = (unsigned short)bf16r(wv.x);
        wtl[(c4 + 1) * 128 + ((kb ^ ((c4 + 1) & 15)) << 3) + kr] = (unsigned short)bf16r(wv.y);
        wtl[(c4 + 2) * 128 + ((kb ^ ((c4 + 2) & 15)) << 3) + kr] = (unsigned short)bf16r(wv.z);
        wtl[(c4 + 3) * 128 + ((kb ^ ((c4 + 3) & 15)) << 3) + kr] = (unsigned short)bf16r(wv.w);
    }

    // phase A2: wt = W@a_top, wb = W@a_bot (exact f32, identical per block)
    if (tid < 128) {
        int k = tid;
        float s = 0.0f, t = 0.0f;
#pragma unroll
        for (int c4 = 0; c4 < 64; c4 += 4) {
            float4 wv = *reinterpret_cast<const float4*>(W + k * 64 + c4);
            float4 at = *reinterpret_cast<const float4*>(a + c4);
            float4 ab = *reinterpret_cast<const float4*>(a + 64 + c4);
            s = fmaf(wv.w, at.w, fmaf(wv.z, at.z, fmaf(wv.y, at.y, fmaf(wv.x, at.x, s))));
            t = fmaf(wv.w, ab.w, fmaf(wv.z, ab.z, fmaf(wv.y, ab.y, fmaf(wv.x, ab.x, t))));
        }
        wt_s[k] = s;
        wb_s[k] = t;
    }

    // phase A3: fused edge histogram (this block's 1024 edges)
    {
        int j0 = blockIdx.x * 1024 + tid * 4;
        if (j0 < N_EDGES) {
            int4 s4 = *reinterpret_cast<const int4*>(src + j0);
            atomicAdd(&hc[s4.x >> 6], 1);
            atomicAdd(&hc[s4.y >> 6], 1);
            atomicAdd(&hc[s4.z >> 6], 1);
            atomicAdd(&hc[s4.w >> 6], 1);
        }
    }
    __syncthreads();

    // phase B: stage x -> xb (bf16, swizzled) + f32 sv/tv partial dots
    const int cc = (tid & 31) << 2;
    float4 wt4 = *reinterpret_cast<const float4*>(wt_s + cc);
    float4 wb4 = *reinterpret_cast<const float4*>(wb_s + cc);
    float ps[8], pt[8];
#pragma unroll
    for (int it = 0; it < 8; ++it) {
        int i = tid + it * 256;
        int rl = i >> 5;
        int r = row0 + rl;
        float4 v = make_float4(0.f, 0.f, 0.f, 0.f);
        if (r < N_NODES) v = *reinterpret_cast<const float4*>(x + (size_t)r * IN_F + cc);
        ps[it] = fmaf(v.w, wt4.w, fmaf(v.z, wt4.z, fmaf(v.y, wt4.y, v.x * wt4.x)));
        pt[it] = fmaf(v.w, wb4.w, fmaf(v.z, wb4.z, fmaf(v.y, wb4.y, v.x * wb4.x)));
        int kb = cc >> 3;
        uint2 pk;
        pk.x = bf16r(v.x) | (bf16r(v.y) << 16);
        pk.y = bf16r(v.z) | (bf16r(v.w) << 16);
        *reinterpret_cast<uint2*>(
            &xb[rl * 128 + (kb ^ (rl & 15)) * 8 + ((cc >> 2) & 1) * 4]) = pk;
    }
    __syncthreads();

    // phase C: MFMA
    const int l = tid & 63, w = tid >> 6;
    const int rloc0 = w * 16;
    const int arow = rloc0 + (l & 15);
    const int kgrp = l >> 4;
    f32x4 acc[4] = {f32x4{0,0,0,0}, f32x4{0,0,0,0}, f32x4{0,0,0,0}, f32x4{0,0,0,0}};
#pragma unroll
    for (int t = 0; t < 4; ++t) {
        int kb = t * 4 + kgrp;
        bf16x8 af = *reinterpret_cast<const bf16x8*>(
            &xb[arow * 128 + (kb ^ (arow & 15)) * 8]);
#pragma unroll
        for (int ct = 0; ct < 4; ++ct) {
            int brow = ct * 16 + (l & 15);
            bf16x8 bfr = *reinterpret_cast<const bf16x8*>(
                &wtl[brow * 128 + (kb ^ (brow & 15)) * 8]);
            acc[ct] = __builtin_amdgcn_mfma_f32_16x16x32_bf16(af, bfr, acc[ct], 0, 0, 0);
        }
    }

#pragma unroll
    for (int ct = 0; ct < 4; ++ct) {
#pragma unroll
        for (int i = 0; i < 4; ++i) {
            int r = row0 + rloc0 + (l >> 4) * 4 + i;
            if (r < N_NODES)
                Whb[(size_t)r * OUT_F + ct * 16 + (l & 15)] =
                    (unsigned short)bf16r(acc[ct][i]);
        }
    }

#pragma unroll
    for (int it = 0; it < 8; ++it) {
        float s = ps[it], t2 = pt[it];
#pragma unroll
        for (int o = 1; o < 32; o <<= 1) {
            s += __shfl_xor(s, o, 64);
            t2 += __shfl_xor(t2, o, 64);
        }
        int r = row0 + (tid >> 5) + it * 8;
        if ((tid & 31) == 0 && r < N_NODES) { sv[r] = s; tv[r] = t2; }
    }

    // flush histogram (hc finalized before first sync)
    for (int i = tid; i < NBUCK; i += 256) {
        int v = hc[i];
        if (v) atomicAdd(&bcnt[i], v);
    }
}

// exclusive scan of 782 bucket counts: shfl-scan per wave + serial combine
__global__ __launch_bounds__(1024) void k_bscan(const int* __restrict__ bcnt,
                                                int* __restrict__ bbase,
                                                int* __restrict__ cursor) {
    __shared__ int wsum[16], woff[16];
    int t = threadIdx.x, lane = t & 63, w = t >> 6;
    int c = (t < NBUCK) ? bcnt[t] : 0;
    int run = c;
#pragma unroll
    for (int o = 1; o < 64; o <<= 1) {
        int v = __shfl_up(run, o, 64);
        if (lane >= o) run += v;
    }
    if (lane == 63) wsum[w] = run;
    __syncthreads();
    if (t == 0) {
        int r = 0;
#pragma unroll
        for (int i = 0; i < 16; i++) { woff[i] = r; r += wsum[i]; }
    }
    __syncthreads();
    int ex = run - c + woff[w];
    if (t < NBUCK) {
        bbase[t] = ex;
        cursor[t] = ex;
    }
    if (t == 0) bbase[NBUCK] = N_EDGES;
}

// bucket scatter: EPT=16; LDS ranks + one global reserve atomic per
// (block,bucket); stores rec = {dst|local<<16, bits(exp(v))} (gmax cancels).
__global__ __launch_bounds__(256) void k_binscatter(const int* __restrict__ src,
                                                    const int* __restrict__ dst,
                                                    const float* __restrict__ sv,
                                                    const float* __restrict__ tv,
                                                    int* __restrict__ cursor,
                                                    int2* __restrict__ rec,
                                                    float* __restrict__ psum) {
    __shared__ int lcnt[NBUCK];
    __shared__ int lbase[NBUCK];
    const int tid = threadIdx.x;
    for (int i = tid; i < NBUCK; i += 256) lcnt[i] = 0;
    __syncthreads();

    int t = blockIdx.x * 256 + tid;
    int j0 = t * EPT;
    bool ok = (j0 < N_EDGES);

    int s_[EPT], d_[EPT], rk[EPT];
    float ev[EPT];
    float lsum = 0.0f;
    if (ok) {
#pragma unroll
        for (int q = 0; q < 4; q++) {
            int4 s4 = *reinterpret_cast<const int4*>(src + j0 + q * 4);
            int4 d4 = *reinterpret_cast<const int4*>(dst + j0 + q * 4);
            s_[q * 4 + 0] = s4.x; s_[q * 4 + 1] = s4.y;
            s_[q * 4 + 2] = s4.z; s_[q * 4 + 3] = s4.w;
            d_[q * 4 + 0] = d4.x; d_[q * 4 + 1] = d4.y;
            d_[q * 4 + 2] = d4.z; d_[q * 4 + 3] = d4.w;
        }
        float svv[EPT], tvv[EPT];
#pragma unroll
        for (int k = 0; k < EPT; k++) svv[k] = sv[s_[k]];
#pragma unroll
        for (int k = 0; k < EPT; k++) tvv[k] = tv[d_[k]];
#pragma unroll
        for (int k = 0; k < EPT; k++) {
            float vv = svv[k] + tvv[k];
            vv = vv > 0.0f ? vv : LRELU_ALPHA * vv;
            float e = __expf(vv);
            ev[k] = e;
            lsum += e;
        }
#pragma unroll
        for (int k = 0; k < EPT; k++) rk[k] = atomicAdd(&lcnt[s_[k] >> 6], 1);
    }
    __syncthreads();

    for (int i = tid; i < NBUCK; i += 256) {
        int c = lcnt[i];
        lbase[i] = c ? atomicAdd(&cursor[i], c) : 0;
    }
    __syncthreads();

    if (ok) {
#pragma unroll
        for (int k = 0; k < EPT; k++) {
            int b = s_[k] >> 6;
            rec[lbase[b] + rk[k]] =
                make_int2(d_[k] | ((s_[k] & (NPB - 1)) << 16), __float_as_int(ev[k]));
        }
    }

    float wsum = wred_sum(lsum);
    __shared__ float rsm[4];
    if ((tid & 63) == 0) rsm[tid >> 6] = wsum;
    __syncthreads();
    if (tid == 0)
        psum[blockIdx.x] = rsm[0] + rsm[1] + rsm[2] + rsm[3];
}

// bucket gather: NPB=64, 512 threads (8 waves), fused 1/sum reduce,
// in-LDS counting sort + half-wave bf16 accumulate (8 edges/iter).
__global__ __launch_bounds__(512) void k_bgather(const int* __restrict__ bbase,
                                                 const int2* __restrict__ rec,
                                                 const float* __restrict__ psum,
                                                 const unsigned short* __restrict__ Whb,
                                                 float* __restrict__ out) {
    __shared__ int2 sorted[CHUNK];               // 16 KB
    __shared__ int scnt[NPB], soff[NPB], shead[NPB];
    __shared__ float ginv_s;

    const int tid = threadIdx.x;
    const int lane = tid & 63, w = tid >> 6;     // wave 0..7
    const int j = lane & 31, h = lane >> 5;      // feature-pair, half id
    const int b = blockIdx.x;
    const int e0 = bbase[b], e1 = bbase[b + 1];

    // fused: ginv = 1 / sum(psum[0..NBT))
    if (tid < 64) {
        float lsum = 0.0f;
        for (int i = tid; i < NBT; i += 64) lsum += psum[i];
        float ws = wred_sum(lsum);
        if (tid == 0) ginv_s = 1.0f / ws;
    }
    __syncthreads();
    const float ginv = ginv_s;

    float ax[8], ay[8];
#pragma unroll
    for (int k = 0; k < 8; k++) { ax[k] = 0.0f; ay[k] = 0.0f; }

    for (int base = e0; base < e1; base += CHUNK) {
        int m = e1 - base;
        if (m > CHUNK) m = CHUNK;

        int2 rr[4];
        int ln[4];
        bool vv[4];
        if (tid < NPB) scnt[tid] = 0;
        __syncthreads();
#pragma unroll
        for (int q = 0; q < 4; q++) {
            int idx = tid + q * 512;
            vv[q] = idx < m;
            rr[q] = make_int2(0, 0);
            ln[q] = 0;
            if (vv[q]) {
                rr[q] = rec[base + idx];
                ln[q] = (rr[q].x >> 16) & (NPB - 1);
                atomicAdd(&scnt[ln[q]], 1);
            }
        }
        __syncthreads();

        if (tid < 64) {
            int c = scnt[tid];
            int run = c;
#pragma unroll
            for (int o = 1; o < 64; o <<= 1) {
                int src_ln = (tid >= o) ? (tid - o) : tid;
                int t2 = __shfl(run, src_ln, 64);
                if (tid >= o) run += t2;
            }
            int excl = run - c;
            soff[tid] = excl;
            shead[tid] = excl;
        }
        __syncthreads();

#pragma unroll
        for (int q = 0; q < 4; q++) {
            if (vv[q]) {
                int pos = atomicAdd(&shead[ln[q]], 1);
                sorted[pos] = make_int2(rr[q].x & 0xFFFF, rr[q].y);
            }
        }
        __syncthreads();

#pragma unroll
        for (int k = 0; k < 8; k++) {
            int node = w * 8 + k;
            int lo = soff[node], c = scnt[node];
            float px = 0.0f, py = 0.0f;
            int i = 0;
            for (; i + 7 < c; i += 8) {
                int2 q0 = sorted[lo + i + h];
                int2 q1 = sorted[lo + i + 2 + h];
                int2 q2 = sorted[lo + i + 4 + h];
                int2 q3 = sorted[lo + i + 6 + h];
                const unsigned* p0 =
                    reinterpret_cast<const unsigned*>(Whb + (size_t)q0.x * OUT_F);
                const unsigned* p1 =
                    reinterpret_cast<const unsigned*>(Whb + (size_t)q1.x * OUT_F);
                const unsigned* p2 =
                    reinterpret_cast<const unsigned*>(Whb + (size_t)q2.x * OUT_F);
                const unsigned* p3 =
                    reinterpret_cast<const unsigned*>(Whb + (size_t)q3.x * OUT_F);
                unsigned u0 = p0[j];
                unsigned u1 = p1[j];
                unsigned u2 = p2[j];
                unsigned u3 = p3[j];
                float att0 = __int_as_float(q0.y);
                float att1 = __int_as_float(q1.y);
                float att2 = __int_as_float(q2.y);
                float att3 = __int_as_float(q3.y);
                px = fmaf(att0, __uint_as_float((u0 & 0xffffu) << 16), px);
                py = fmaf(att0, __uint_as_float(u0 & 0xffff0000u), py);
                px = fmaf(att1, __uint_as_float((u1 & 0xffffu) << 16), px);
                py = fmaf(att1, __uint_as_float(u1 & 0xffff0000u), py);
                px = fmaf(att2, __uint_as_float((u2 & 0xffffu) << 16), px);
                py = fmaf(att2, __uint_as_float(u2 & 0xffff0000u), py);
                px = fmaf(att3, __uint_as_float((u3 & 0xffffu) << 16), px);
                py = fmaf(att3, __uint_as_float(u3 & 0xffff0000u), py);
            }
            for (; i < c; i += 2) {
                int ii = i + h;
                bool val = ii < c;
                int2 q = sorted[lo + (val ? ii : i)];
                const unsigned* p =
                    reinterpret_cast<const unsigned*>(Whb + (size_t)q.x * OUT_F);
                unsigned u = p[j];
                float att = val ? __int_as_float(q.y) : 0.0f;
                px = fmaf(att, __uint_as_float((u & 0xffffu) << 16), px);
                py = fmaf(att, __uint_as_float(u & 0xffff0000u), py);
            }
            ax[k] += px;
            ay[k] += py;
        }
        __syncthreads();
    }

#pragma unroll
    for (int k = 0; k < 8; k++) {
        float sx = ax[k] + __shfl_down(ax[k], 32, 64);
        float sy = ay[k] + __shfl_down(ay[k], 32, 64);
        int n = b * NPB + w * 8 + k;
        if (h == 0 && n < N_NODES) {
            float2 v;
            v.x = sx * ginv;
            v.y = sy * ginv;
            v.x = v.x > 0.0f ? v.x : expm1f(v.x);
            v.y = v.y > 0.0f ? v.y : expm1f(v.y);
            *reinterpret_cast<float2*>(out + (size_t)n * OUT_F + 2 * j) = v;
        }
    }
}

extern "C" void kernel_launch(void* const* d_in, const int* in_sizes, int n_in,
                              void* d_out, int out_size, void* d_ws, size_t ws_size,
                              hipStream_t stream) {
    const float* x  = (const float*)d_in[0];
    const int*   ei = (const int*)d_in[1];
    const float* W  = (const float*)d_in[2];
    const float* a  = (const float*)d_in[3];
    float* out = (float*)d_out;

    const int* src = ei;            // edge_index[0]
    const int* dst = ei + N_EDGES;  // edge_index[1]

    unsigned short* Whb = (unsigned short*)d_ws;      // 3,200,000 u16 = 6.4 MB
    float* sv     = (float*)(Whb + (size_t)N_NODES * OUT_F);  // 50,000 f
    float* tv     = sv + N_NODES;                     // 50,000 f
    float* psum   = tv + N_NODES;                     // 512 f
    int*   bcnt   = (int*)(psum + 512);               // NBUCK i
    int*   bbase  = bcnt + NBUCK;                     // NBUCK+1 i
    int*   cursor = bbase + NBUCK + 1;                // NBUCK i
    size_t used = (size_t)((char*)(cursor + NBUCK) - (char*)d_ws);
    used = (used + 15) & ~(size_t)15;
    int2*  rec  = (int2*)((char*)d_ws + used);        // 800,000 int2 = 6.4 MB

    hipMemsetAsync(bcnt, 0, NBUCK * sizeof(int), stream);
    k_wh<<<(N_NODES + 63) / 64, 256, 0, stream>>>(x, W, a, src, Whb, sv, tv, bcnt);
    k_bscan<<<1, 1024, 0, stream>>>(bcnt, bbase, cursor);
    k_binscatter<<<NBT, 256, 0, stream>>>(src, dst, sv, tv, cursor, rec, psum);
    k_bgather<<<NBUCK, 512, 0, stream>>>(bbase, rec, psum, Whb, out);
}